// Round 5
// baseline (259.570 us; speedup 1.0000x reference)
//
#include <hip/hip_runtime.h>
#include <math.h>

#define NPTS 20000
#define KNB  32
#define DDIM 64
#define HIDN 64
#define OUTC 192
#define PPB  4

// d_ws layout, ushort units (bf16 MFMA fragments, 512 ushorts = 1 frag)
#define WS_W2 0        // 8 frags  (ct*2+ks)
#define WS_W3 4096     // 8 frags
#define WS_W1 8192     // 4 frags  (ct)
#define WS_WG 10240    // 24 frags (ot*2+ks)
#define WS_WV 22528    // 24 frags (ot*2+ks)
#define WS_FEATS 34816            // ushort offset of bf16 s_feats [M][192]
#define WS_NEED  (69632 + (size_t)NPTS*192*2)   // 7,749,632 bytes

typedef short bf16x8 __attribute__((ext_vector_type(8)));
typedef float f32x4  __attribute__((ext_vector_type(4)));

union BF8 { bf16x8 v; unsigned short us[8]; unsigned u[4]; };

__device__ __forceinline__ unsigned short f2bf(float f) {  // RNE, finite inputs
  unsigned u = __builtin_bit_cast(unsigned, f);
  u += 0x7fffu + ((u >> 16) & 1u);
  return (unsigned short)(u >> 16);
}
__device__ __forceinline__ float bfhi2f(unsigned hi) {     // hi = bf16 bits in [31:16]
  return __builtin_bit_cast(float, hi);
}

__device__ __forceinline__ float fast_atan2pi(float y, float x) {
  // y >= 0; returns atan2(y,x)/pi; abs err ~1e-6
  const float ax = fabsf(x);
  const float mx = fmaxf(fmaxf(ax, y), 1e-30f);
  const float mn = fminf(ax, y);
  const float t  = mn * __builtin_amdgcn_rcpf(mx);
  const float s  = t * t;
  float p = -0.0117212f;
  p = fmaf(p, s,  0.05265332f);
  p = fmaf(p, s, -0.11643287f);
  p = fmaf(p, s,  0.19354346f);
  p = fmaf(p, s, -0.33262347f);
  p = fmaf(p, s,  0.99997726f);
  float r = p * t;
  if (y > ax)  r = 1.5707963268f - r;
  if (x < 0.f) r = 3.1415926536f - r;
  return r * 0.3183098862f;
}

__device__ __forceinline__ float angle3f(float ax, float ay, float az,
                                         float bx, float by, float bz) {
  const float y  = ax*bx + ay*by + az*bz;
  const float cx = ay*bz - az*by;
  const float cy = az*bx - ax*bz;
  const float cz = ax*by - ay*bx;
  const float xn = __builtin_amdgcn_sqrtf(cx*cx + cy*cy + cz*cz);
  return fast_atan2pi(xn, y);
}

// ---- prep: weights -> bf16 fragment layout in d_ws --------------------------
__global__ void prep_weights(const float* __restrict__ W1, const float* __restrict__ W2,
                             const float* __restrict__ W3, const float* __restrict__ Wg,
                             const float* __restrict__ Wv, unsigned short* __restrict__ ws)
{
  const int f  = blockIdx.x;     // 68 frags
  const int L  = threadIdx.x;    // 64 lanes
  const int ln = L & 15, lq = L >> 4;
  unsigned short vals[8];
  if (f >= 16 && f < 20) {       // W1 [64][4], K padded to 32
    const int ct = f - 16;
#pragma unroll
    for (int j = 0; j < 8; ++j) {
      const float v = (lq == 0 && j < 4) ? W1[(ln + 16*ct)*4 + j] : 0.f;
      vals[j] = f2bf(v);
    }
  } else {
    const float* M; int q;
    if (f < 8)       { M = W2; q = f; }
    else if (f < 16) { M = W3; q = f - 8; }
    else if (f < 44) { M = Wg; q = f - 20; }
    else             { M = Wv; q = f - 44; }
    const int ct = q >> 1, ks = q & 1;
    const float* src = M + (ln + 16*ct)*64 + lq*8 + 32*ks;
#pragma unroll
    for (int j = 0; j < 8; ++j) vals[j] = f2bf(src[j]);
  }
  uint4 w;
  w.x = vals[0] | ((unsigned)vals[1] << 16);
  w.y = vals[2] | ((unsigned)vals[3] << 16);
  w.z = vals[4] | ((unsigned)vals[5] << 16);
  w.w = vals[6] | ((unsigned)vals[7] << 16);
  *(uint4*)&ws[f*512 + L*8] = w;
}

// ---- prep: s_feats fp32 -> bf16 [M][192], contiguous 384 B rows -------------
__global__ __launch_bounds__(256) void prep_feats(const float* __restrict__ sf,
                                                  unsigned short* __restrict__ dst) {
  const int i = (blockIdx.x * 256 + threadIdx.x) * 8;   // 8 floats per thread
  const float4 x = *(const float4*)&sf[i];
  const float4 y = *(const float4*)&sf[i + 4];
  uint4 w;
  w.x = f2bf(x.x) | ((unsigned)f2bf(x.y) << 16);
  w.y = f2bf(x.z) | ((unsigned)f2bf(x.w) << 16);
  w.z = f2bf(y.x) | ((unsigned)f2bf(y.y) << 16);
  w.w = f2bf(y.z) | ((unsigned)f2bf(y.w) << 16);
  *(uint4*)&dst[i] = w;
}

// ---- main fused kernel ------------------------------------------------------
template<bool BF>
__global__ __launch_bounds__(256, 5)
void ppf_fused(const float* __restrict__ q_pts,
               const float* __restrict__ s_pts,
               const float* __restrict__ s_feats,
               const int*   __restrict__ nbr,
               const float* __restrict__ normals,
               const float* __restrict__ b1, const float* __restrict__ b2,
               const float* __restrict__ b3, const float* __restrict__ bg,
               const unsigned short* __restrict__ wsu,
               float* __restrict__ out)
{
  // s_h rows: cols 0..63 = h tile (bf16); cols 64..71 = this row's ppf float4.
  __shared__ __align__(16) unsigned short s_h[PPB][KNB][72];   // 18432 B (alias s_out)
  __shared__ __align__(16) unsigned short s_modb[16][72];      //  2304 B
  __shared__ __align__(16) unsigned short s_aggb[16][72];      //  2304 B rows=(g,t)
  __shared__ float s_gate[PPB][200];                           //  3200 B
  float* s_out = (float*)&s_h[0][0][0];                        // 4 x 592 floats

  const int tid  = threadIdx.x;
  const int g    = tid >> 6;
  const int lane = tid & 63;
  const int lq   = lane >> 4;
  const int ln   = lane & 15;
  const int pu   = __builtin_amdgcn_readfirstlane(blockIdx.x * PPB + g);

  // Gather state: single buffer, 8 rows per chunk.
  uint2  bufH[8];            // BF path: 16 VGPRs
  float3 bufF[8];            // fp32 path: 24 VGPRs
  float a0 = 0.f, a1 = 0.f, a2 = 0.f, a3 = 0.f;   // BF: elems 4*lane..4*lane+3
  float s0 = 0.f, s1 = 0.f, s2 = 0.f;             // fp32: (d=lane, t=0..2)
  const unsigned short* fb = wsu + WS_FEATS;

  auto issue = [&](int base) {
    if constexpr (BF) {
      if (lane < 48) {
#pragma unroll
        for (int k = 0; k < 8; ++k) {
          const int mi = nbr[pu*KNB + base + k];          // uniform -> s_load
          bufH[k] = *(const uint2*)&fb[(size_t)mi*192 + lane*4];
        }
      }
    } else {
#pragma unroll
      for (int k = 0; k < 8; ++k) {
        const int mi = nbr[pu*KNB + base + k];
        const float* fr = s_feats + (size_t)mi*(DDIM*3) + lane*3;
        bufF[k] = make_float3(fr[0], fr[1], fr[2]);
      }
    }
  };
  auto acc = [&]() {
    if constexpr (BF) {
#pragma unroll
      for (int k = 0; k < 8; ++k) {
        const unsigned x = bufH[k].x, y = bufH[k].y;
        a0 += bfhi2f(x << 16); a1 += bfhi2f(x & 0xffff0000u);
        a2 += bfhi2f(y << 16); a3 += bfhi2f(y & 0xffff0000u);
      }
    } else {
#pragma unroll
      for (int k = 0; k < 8; ++k) { s0 += bufF[k].x; s1 += bufF[k].y; s2 += bufF[k].z; }
    }
  };

  issue(0);   // chunk 0 in flight across phase A + layer 1

  // ---- Phase A: PPF features, split across wave halves ----------------------
  {
    const float qx = q_pts[pu*3+0], qy = q_pts[pu*3+1], qz = q_pts[pu*3+2];
    const int   i0 = nbr[pu*KNB];
    const float qnx = normals[i0*3+0], qny = normals[i0*3+1], qnz = normals[i0*3+2];
    const int k  = lane & 31;
    const int mi = nbr[pu*KNB + k];
    const float px = s_pts[mi*3+0], py = s_pts[mi*3+1], pz = s_pts[mi*3+2];
    const float nx = normals[mi*3+0], ny = normals[mi*3+1], nz = normals[mi*3+2];
    const float vx = px - qx, vy = py - qy, vz = pz - qz;
    float* ppfrow = (float*)&s_h[g][k][64];
    if (lane < KNB) {
      ppfrow[1] = angle3f(qnx,qny,qnz, vx,vy,vz);
      ppfrow[2] = angle3f(nx,ny,nz,    vx,vy,vz);
    } else {
      ppfrow[0] = __builtin_amdgcn_sqrtf(vx*vx + vy*vy + vz*vz);
      ppfrow[3] = angle3f(qnx,qny,qnz, nx,ny,nz);
    }
  }
  // ppf produced/consumed by the same wave; per-wave DS ops are in order.

  // ---- Layer 1: h1 = relu(ppf @ W1^T + b1) via MFMA -------------------------
  {
    BF8 a1f[2];
    a1f[0].u[0]=a1f[0].u[1]=a1f[0].u[2]=a1f[0].u[3]=0;
    a1f[1] = a1f[0];
    if (lq == 0) {
#pragma unroll
      for (int rt = 0; rt < 2; ++rt) {
        const float4 pv = *(const float4*)&s_h[g][ln + 16*rt][64];
        a1f[rt].us[0]=f2bf(pv.x); a1f[rt].us[1]=f2bf(pv.y);
        a1f[rt].us[2]=f2bf(pv.z); a1f[rt].us[3]=f2bf(pv.w);
      }
    }
#pragma unroll
    for (int ct = 0; ct < 4; ++ct) {
      const bf16x8 bw = *(const bf16x8*)&wsu[WS_W1 + ct*512 + lane*8];
      const float  bv = b1[ln + 16*ct];
#pragma unroll
      for (int rt = 0; rt < 2; ++rt) {
        f32x4 c = {bv, bv, bv, bv};
        c = __builtin_amdgcn_mfma_f32_16x16x32_bf16(a1f[rt].v, bw, c, 0, 0, 0);
#pragma unroll
        for (int r = 0; r < 4; ++r)
          s_h[g][lq*4 + r + 16*rt][ln + 16*ct] = f2bf(fmaxf(c[r], 0.f));
      }
    }
  }

  acc();       // consume chunk 0 (waits its vmcnt)
  issue(8);    // chunk 1 in flight across layer 2

  // ---- Layer 2: h2 = relu(h1 @ W2^T + b2), in place -------------------------
  {
    bf16x8 wf[8];
#pragma unroll
    for (int fIdx = 0; fIdx < 8; ++fIdx)
      wf[fIdx] = *(const bf16x8*)&wsu[WS_W2 + fIdx*512 + lane*8];
    bf16x8 af[4];
#pragma unroll
    for (int rt = 0; rt < 2; ++rt)
#pragma unroll
      for (int ks = 0; ks < 2; ++ks)
        af[rt*2+ks] = *(const bf16x8*)&s_h[g][ln + 16*rt][lq*8 + ks*32];
#pragma unroll
    for (int ct = 0; ct < 4; ++ct) {
      const float bv = b2[ln + 16*ct];
#pragma unroll
      for (int rt = 0; rt < 2; ++rt) {
        f32x4 c = {bv, bv, bv, bv};
        c = __builtin_amdgcn_mfma_f32_16x16x32_bf16(af[rt*2+0], wf[ct*2+0], c, 0, 0, 0);
        c = __builtin_amdgcn_mfma_f32_16x16x32_bf16(af[rt*2+1], wf[ct*2+1], c, 0, 0, 0);
#pragma unroll
        for (int r = 0; r < 4; ++r)
          s_h[g][lq*4 + r + 16*rt][ln + 16*ct] = f2bf(fmaxf(c[r], 0.f));
      }
    }
  }

  acc();       // consume chunk 1
  issue(16);   // chunk 2 in flight across layer 3

  // ---- Layer 3 + fused mean over K -> s_modb --------------------------------
  {
    bf16x8 wf[8];
#pragma unroll
    for (int fIdx = 0; fIdx < 8; ++fIdx)
      wf[fIdx] = *(const bf16x8*)&wsu[WS_W3 + fIdx*512 + lane*8];
    bf16x8 af[4];
#pragma unroll
    for (int rt = 0; rt < 2; ++rt)
#pragma unroll
      for (int ks = 0; ks < 2; ++ks)
        af[rt*2+ks] = *(const bf16x8*)&s_h[g][ln + 16*rt][lq*8 + ks*32];
#pragma unroll
    for (int ct = 0; ct < 4; ++ct) {
      const float bv = b3[ln + 16*ct];
      f32x4 c0 = {bv, bv, bv, bv};
      c0 = __builtin_amdgcn_mfma_f32_16x16x32_bf16(af[0], wf[ct*2+0], c0, 0, 0, 0);
      c0 = __builtin_amdgcn_mfma_f32_16x16x32_bf16(af[1], wf[ct*2+1], c0, 0, 0, 0);
      f32x4 c1 = {bv, bv, bv, bv};
      c1 = __builtin_amdgcn_mfma_f32_16x16x32_bf16(af[2], wf[ct*2+0], c1, 0, 0, 0);
      c1 = __builtin_amdgcn_mfma_f32_16x16x32_bf16(af[3], wf[ct*2+1], c1, 0, 0, 0);
      float s = (c0[0]+c0[1]+c0[2]+c0[3]) + (c1[0]+c1[1]+c1[2]+c1[3]);
      s += __shfl_xor(s, 16);
      s += __shfl_xor(s, 32);
      if (lq == 0) s_modb[g][ln + 16*ct] = f2bf(s * (1.f/KNB));
    }
  }

  acc();       // consume chunk 2
  issue(24);   // chunk 3
  acc();       // consume chunk 3 (one exposed miss round)

  // ---- Write aggregated means to s_aggb (bf16, row n=(g,t), col=d) ----------
  if constexpr (BF) {
    if (lane < 48) {
      float av[4] = {a0, a1, a2, a3};
#pragma unroll
      for (int j = 0; j < 4; ++j) {
        const int e = 4*lane + j;            // e = d*3 + t
        s_aggb[g*3 + (e % 3)][e / 3] = f2bf(av[j] * (1.f/KNB));
      }
    }
  } else {
    s_aggb[g*3+0][lane] = f2bf(s0 * (1.f/KNB));
    s_aggb[g*3+1][lane] = f2bf(s1 * (1.f/KNB));
    s_aggb[g*3+2][lane] = f2bf(s2 * (1.f/KNB));
  }

  __syncthreads();   // s_modb/s_aggb cross-wave; all s_h frag reads drained

  // ---- Gate via MFMA: rows = points (4 valid), cols = 192 outputs -----------
  {
    const bf16x8 am0 = *(const bf16x8*)&s_modb[ln][lq*8];
    const bf16x8 am1 = *(const bf16x8*)&s_modb[ln][lq*8 + 32];
#pragma unroll
    for (int t = 0; t < 3; ++t) {
      const int ot = g*3 + t;
      const bf16x8 bg0 = *(const bf16x8*)&wsu[WS_WG + (ot*2+0)*512 + lane*8];
      const bf16x8 bg1 = *(const bf16x8*)&wsu[WS_WG + (ot*2+1)*512 + lane*8];
      const float  bv  = bg[ln + 16*ot];
      f32x4 c = {bv, bv, bv, bv};
      c = __builtin_amdgcn_mfma_f32_16x16x32_bf16(am0, bg0, c, 0, 0, 0);
      c = __builtin_amdgcn_mfma_f32_16x16x32_bf16(am1, bg1, c, 0, 0, 0);
      if (lq == 0) {
#pragma unroll
        for (int r = 0; r < 4; ++r)
          s_gate[r][ln + 16*ot] = 1.f / (1.f + __expf(-c[r]));
      }
    }
  }

  // ---- Transform via MFMA: rows = outputs, cols = (point,t) -----------------
  {
    const bf16x8 ab0 = *(const bf16x8*)&s_aggb[ln][lq*8];
    const bf16x8 ab1 = *(const bf16x8*)&s_aggb[ln][lq*8 + 32];
    const int gi = ln / 3;            // valid for ln < 12
    const int tt = ln - gi*3;
#pragma unroll
    for (int t2 = 0; t2 < 3; ++t2) {
      const int ot = g*3 + t2;
      const bf16x8 av0 = *(const bf16x8*)&wsu[WS_WV + (ot*2+0)*512 + lane*8];
      const bf16x8 av1 = *(const bf16x8*)&wsu[WS_WV + (ot*2+1)*512 + lane*8];
      f32x4 c = {0.f, 0.f, 0.f, 0.f};
      c = __builtin_amdgcn_mfma_f32_16x16x32_bf16(av0, ab0, c, 0, 0, 0);
      c = __builtin_amdgcn_mfma_f32_16x16x32_bf16(av1, ab1, c, 0, 0, 0);
      if (ln < 12) {
#pragma unroll
        for (int r = 0; r < 4; ++r) {
          const int o = 16*ot + lq*4 + r;
          s_out[gi*592 + o*3 + tt] = c[r] * s_gate[gi][o];
        }
      }
    }
  }
  __syncthreads();

  // ---- Coalesced float4 output write ----------------------------------------
  {
    float4* outv = (float4*)out;
    const float4* sov = (const float4*)s_out;
#pragma unroll
    for (int i = 0; i < 3; ++i) {
      const int idx = tid + 256*i;
      if (idx < 576) {
        const int gg  = idx / 144;
        const int off = idx - gg*144;
        outv[(size_t)blockIdx.x * 576 + idx] = sov[gg*148 + off];
      }
    }
  }
}

extern "C" void kernel_launch(void* const* d_in, const int* in_sizes, int n_in,
                              void* d_out, int out_size, void* d_ws, size_t ws_size,
                              hipStream_t stream) {
  const float* q_pts   = (const float*)d_in[0];
  const float* s_pts   = (const float*)d_in[1];
  const float* s_feats = (const float*)d_in[2];
  const int*   nbr     = (const int*)  d_in[3];
  const float* normals = (const float*)d_in[4];
  const float* W1 = (const float*)d_in[5];
  const float* b1 = (const float*)d_in[6];
  const float* W2 = (const float*)d_in[7];
  const float* b2 = (const float*)d_in[8];
  const float* W3 = (const float*)d_in[9];
  const float* b3 = (const float*)d_in[10];
  const float* Wg = (const float*)d_in[11];
  const float* bg = (const float*)d_in[12];
  const float* Wv = (const float*)d_in[13];
  float* out = (float*)d_out;
  unsigned short* ws = (unsigned short*)d_ws;

  hipLaunchKernelGGL(prep_weights, dim3(68), dim3(64), 0, stream,
                     W1, W2, W3, Wg, Wv, ws);
  if (ws_size >= WS_NEED) {
    // 20000*192 floats / 8 per thread / 256 per block = 1875 blocks exactly
    hipLaunchKernelGGL(prep_feats, dim3(1875), dim3(256), 0, stream,
                       s_feats, ws + WS_FEATS);
    hipLaunchKernelGGL(ppf_fused<true>, dim3(NPTS / PPB), dim3(256), 0, stream,
                       q_pts, s_pts, s_feats, nbr, normals,
                       b1, b2, b3, bg, ws, out);
  } else {
    hipLaunchKernelGGL(ppf_fused<false>, dim3(NPTS / PPB), dim3(256), 0, stream,
                       q_pts, s_pts, s_feats, nbr, normals,
                       b1, b2, b3, bg, ws, out);
  }
}

// Round 6
// 158.973 us; speedup vs baseline: 1.6328x; 1.6328x over previous
//
#include <hip/hip_runtime.h>
#include <math.h>

#define NPTS 20000
#define KNB  32
#define DDIM 64
#define HIDN 64
#define OUTC 192
#define PPB  4

// d_ws layout, ushort units (bf16 MFMA fragments, 512 ushorts = 1 frag)
#define WS_W2 0        // 8 frags  (ct*2+ks)
#define WS_W3 4096     // 8 frags
#define WS_W1 8192     // 4 frags  (ct)
#define WS_WG 10240    // 24 frags (ot*2+ks)
#define WS_WV 22528    // 24 frags (ot*2+ks)
#define WS_FEATS 34816            // ushort offset of bf16 s_feats [M][192]
#define WS_NEED  (69632 + (size_t)NPTS*192*2)   // 7,749,632 bytes

typedef short bf16x8 __attribute__((ext_vector_type(8)));
typedef float f32x4  __attribute__((ext_vector_type(4)));

union BF8 { bf16x8 v; unsigned short us[8]; unsigned u[4]; };

__device__ __forceinline__ unsigned short f2bf(float f) {  // RNE, finite inputs
  unsigned u = __builtin_bit_cast(unsigned, f);
  u += 0x7fffu + ((u >> 16) & 1u);
  return (unsigned short)(u >> 16);
}
__device__ __forceinline__ float bfhi2f(unsigned hi) {     // hi = bf16 bits in [31:16]
  return __builtin_bit_cast(float, hi);
}

__device__ __forceinline__ float fast_atan2pi(float y, float x) {
  // y >= 0; returns atan2(y,x)/pi; abs err ~1e-6
  const float ax = fabsf(x);
  const float mx = fmaxf(fmaxf(ax, y), 1e-30f);
  const float mn = fminf(ax, y);
  const float t  = mn * __builtin_amdgcn_rcpf(mx);
  const float s  = t * t;
  float p = -0.0117212f;
  p = fmaf(p, s,  0.05265332f);
  p = fmaf(p, s, -0.11643287f);
  p = fmaf(p, s,  0.19354346f);
  p = fmaf(p, s, -0.33262347f);
  p = fmaf(p, s,  0.99997726f);
  float r = p * t;
  if (y > ax)  r = 1.5707963268f - r;
  if (x < 0.f) r = 3.1415926536f - r;
  return r * 0.3183098862f;
}

__device__ __forceinline__ float angle3f(float ax, float ay, float az,
                                         float bx, float by, float bz) {
  const float y  = ax*bx + ay*by + az*bz;
  const float cx = ay*bz - az*by;
  const float cy = az*bx - ax*bz;
  const float cz = ax*by - ay*bx;
  const float xn = __builtin_amdgcn_sqrtf(cx*cx + cy*cy + cz*cz);
  return fast_atan2pi(xn, y);
}

// ---- prep: weights -> bf16 fragment layout in d_ws --------------------------
__global__ void prep_weights(const float* __restrict__ W1, const float* __restrict__ W2,
                             const float* __restrict__ W3, const float* __restrict__ Wg,
                             const float* __restrict__ Wv, unsigned short* __restrict__ ws)
{
  const int f  = blockIdx.x;     // 68 frags
  const int L  = threadIdx.x;    // 64 lanes
  const int ln = L & 15, lq = L >> 4;
  unsigned short vals[8];
  if (f >= 16 && f < 20) {       // W1 [64][4], K padded to 32
    const int ct = f - 16;
#pragma unroll
    for (int j = 0; j < 8; ++j) {
      const float v = (lq == 0 && j < 4) ? W1[(ln + 16*ct)*4 + j] : 0.f;
      vals[j] = f2bf(v);
    }
  } else {
    const float* M; int q;
    if (f < 8)       { M = W2; q = f; }
    else if (f < 16) { M = W3; q = f - 8; }
    else if (f < 44) { M = Wg; q = f - 20; }
    else             { M = Wv; q = f - 44; }
    const int ct = q >> 1, ks = q & 1;
    const float* src = M + (ln + 16*ct)*64 + lq*8 + 32*ks;
#pragma unroll
    for (int j = 0; j < 8; ++j) vals[j] = f2bf(src[j]);
  }
  uint4 w;
  w.x = vals[0] | ((unsigned)vals[1] << 16);
  w.y = vals[2] | ((unsigned)vals[3] << 16);
  w.z = vals[4] | ((unsigned)vals[5] << 16);
  w.w = vals[6] | ((unsigned)vals[7] << 16);
  *(uint4*)&ws[f*512 + L*8] = w;
}

// ---- prep: s_feats fp32 -> bf16 [M][192], contiguous 384 B rows -------------
__global__ __launch_bounds__(256) void prep_feats(const float* __restrict__ sf,
                                                  unsigned short* __restrict__ dst) {
  const int i = (blockIdx.x * 256 + threadIdx.x) * 8;   // 8 floats per thread
  const float4 x = *(const float4*)&sf[i];
  const float4 y = *(const float4*)&sf[i + 4];
  uint4 w;
  w.x = f2bf(x.x) | ((unsigned)f2bf(x.y) << 16);
  w.y = f2bf(x.z) | ((unsigned)f2bf(x.w) << 16);
  w.z = f2bf(y.x) | ((unsigned)f2bf(y.y) << 16);
  w.w = f2bf(y.z) | ((unsigned)f2bf(y.w) << 16);
  *(uint4*)&dst[i] = w;
}

// ---- main fused kernel ------------------------------------------------------
// NOTE: no gather buffers live across phases, and no gather helper functions —
// both r4 (ptr arg) and r5 (lambda by-ref) made the buffer address-taken,
// defeating SROA -> scratch spill (~320 MB WRITE_SIZE). Inline loop only.
template<bool BF>
__global__ __launch_bounds__(256, 6)
void ppf_fused(const float* __restrict__ q_pts,
               const float* __restrict__ s_pts,
               const float* __restrict__ s_feats,
               const int*   __restrict__ nbr,
               const float* __restrict__ normals,
               const float* __restrict__ b1, const float* __restrict__ b2,
               const float* __restrict__ b3, const float* __restrict__ bg,
               const unsigned short* __restrict__ wsu,
               float* __restrict__ out)
{
  // s_h rows: cols 0..63 = h tile (bf16); cols 64..71 = this row's ppf float4.
  __shared__ __align__(16) unsigned short s_h[PPB][KNB][72];   // 18432 B (alias s_out)
  __shared__ __align__(16) unsigned short s_modb[16][72];      //  2304 B
  __shared__ __align__(16) unsigned short s_aggb[16][72];      //  2304 B rows=(g,t)
  __shared__ float s_gate[PPB][200];                           //  3200 B
  float* s_out = (float*)&s_h[0][0][0];                        // 4 x 592 floats

  const int tid  = threadIdx.x;
  const int g    = tid >> 6;
  const int lane = tid & 63;
  const int lq   = lane >> 4;
  const int ln   = lane & 15;
  const int pu   = __builtin_amdgcn_readfirstlane(blockIdx.x * PPB + g);

  // ---- Phase A: PPF features, split across wave halves ----------------------
  {
    const float qx = q_pts[pu*3+0], qy = q_pts[pu*3+1], qz = q_pts[pu*3+2];
    const int   i0 = nbr[pu*KNB];
    const float qnx = normals[i0*3+0], qny = normals[i0*3+1], qnz = normals[i0*3+2];
    const int k  = lane & 31;
    const int mi = nbr[pu*KNB + k];
    const float px = s_pts[mi*3+0], py = s_pts[mi*3+1], pz = s_pts[mi*3+2];
    const float nx = normals[mi*3+0], ny = normals[mi*3+1], nz = normals[mi*3+2];
    const float vx = px - qx, vy = py - qy, vz = pz - qz;
    float* ppfrow = (float*)&s_h[g][k][64];
    if (lane < KNB) {
      ppfrow[1] = angle3f(qnx,qny,qnz, vx,vy,vz);
      ppfrow[2] = angle3f(nx,ny,nz,    vx,vy,vz);
    } else {
      ppfrow[0] = __builtin_amdgcn_sqrtf(vx*vx + vy*vy + vz*vz);
      ppfrow[3] = angle3f(qnx,qny,qnz, nx,ny,nz);
    }
  }
  // ppf produced/consumed by the same wave; per-wave DS ops are in order.

  // ---- Layer 1: h1 = relu(ppf @ W1^T + b1) via MFMA -------------------------
  {
    BF8 a1f[2];
    a1f[0].u[0]=a1f[0].u[1]=a1f[0].u[2]=a1f[0].u[3]=0;
    a1f[1] = a1f[0];
    if (lq == 0) {
#pragma unroll
      for (int rt = 0; rt < 2; ++rt) {
        const float4 pv = *(const float4*)&s_h[g][ln + 16*rt][64];
        a1f[rt].us[0]=f2bf(pv.x); a1f[rt].us[1]=f2bf(pv.y);
        a1f[rt].us[2]=f2bf(pv.z); a1f[rt].us[3]=f2bf(pv.w);
      }
    }
#pragma unroll
    for (int ct = 0; ct < 4; ++ct) {
      const bf16x8 bw = *(const bf16x8*)&wsu[WS_W1 + ct*512 + lane*8];
      const float  bv = b1[ln + 16*ct];
#pragma unroll
      for (int rt = 0; rt < 2; ++rt) {
        f32x4 c = {bv, bv, bv, bv};
        c = __builtin_amdgcn_mfma_f32_16x16x32_bf16(a1f[rt].v, bw, c, 0, 0, 0);
#pragma unroll
        for (int r = 0; r < 4; ++r)
          s_h[g][lq*4 + r + 16*rt][ln + 16*ct] = f2bf(fmaxf(c[r], 0.f));
      }
    }
  }

  // ---- Layer 2: h2 = relu(h1 @ W2^T + b2), in place -------------------------
  // (in-place safe: the wave's 4 A-frag ds_reads precede all its ds_writes)
  {
    bf16x8 wf[8];
#pragma unroll
    for (int fIdx = 0; fIdx < 8; ++fIdx)
      wf[fIdx] = *(const bf16x8*)&wsu[WS_W2 + fIdx*512 + lane*8];
    bf16x8 af[4];
#pragma unroll
    for (int rt = 0; rt < 2; ++rt)
#pragma unroll
      for (int ks = 0; ks < 2; ++ks)
        af[rt*2+ks] = *(const bf16x8*)&s_h[g][ln + 16*rt][lq*8 + ks*32];
#pragma unroll
    for (int ct = 0; ct < 4; ++ct) {
      const float bv = b2[ln + 16*ct];
#pragma unroll
      for (int rt = 0; rt < 2; ++rt) {
        f32x4 c = {bv, bv, bv, bv};
        c = __builtin_amdgcn_mfma_f32_16x16x32_bf16(af[rt*2+0], wf[ct*2+0], c, 0, 0, 0);
        c = __builtin_amdgcn_mfma_f32_16x16x32_bf16(af[rt*2+1], wf[ct*2+1], c, 0, 0, 0);
#pragma unroll
        for (int r = 0; r < 4; ++r)
          s_h[g][lq*4 + r + 16*rt][ln + 16*ct] = f2bf(fmaxf(c[r], 0.f));
      }
    }
  }

  // ---- Layer 3 + fused mean over K -> s_modb --------------------------------
  {
    bf16x8 wf[8];
#pragma unroll
    for (int fIdx = 0; fIdx < 8; ++fIdx)
      wf[fIdx] = *(const bf16x8*)&wsu[WS_W3 + fIdx*512 + lane*8];
    bf16x8 af[4];
#pragma unroll
    for (int rt = 0; rt < 2; ++rt)
#pragma unroll
      for (int ks = 0; ks < 2; ++ks)
        af[rt*2+ks] = *(const bf16x8*)&s_h[g][ln + 16*rt][lq*8 + ks*32];
#pragma unroll
    for (int ct = 0; ct < 4; ++ct) {
      const float bv = b3[ln + 16*ct];
      f32x4 c0 = {bv, bv, bv, bv};
      c0 = __builtin_amdgcn_mfma_f32_16x16x32_bf16(af[0], wf[ct*2+0], c0, 0, 0, 0);
      c0 = __builtin_amdgcn_mfma_f32_16x16x32_bf16(af[1], wf[ct*2+1], c0, 0, 0, 0);
      f32x4 c1 = {bv, bv, bv, bv};
      c1 = __builtin_amdgcn_mfma_f32_16x16x32_bf16(af[2], wf[ct*2+0], c1, 0, 0, 0);
      c1 = __builtin_amdgcn_mfma_f32_16x16x32_bf16(af[3], wf[ct*2+1], c1, 0, 0, 0);
      float s = (c0[0]+c0[1]+c0[2]+c0[3]) + (c1[0]+c1[1]+c1[2]+c1[3]);
      s += __shfl_xor(s, 16);
      s += __shfl_xor(s, 32);
      if (lq == 0) s_modb[g][ln + 16*ct] = f2bf(s * (1.f/KNB));
    }
  }

  // ---- Neighbor-feature mean (inline loop; latency hidden by other waves) ---
  if constexpr (BF) {
    if (lane < 48) {
      float a0 = 0.f, a1 = 0.f, a2 = 0.f, a3 = 0.f;
      const unsigned short* fb = wsu + WS_FEATS;
      const int co = lane * 4;
#pragma unroll 8
      for (int k = 0; k < KNB; ++k) {
        const int mi = nbr[pu*KNB + k];              // wave-uniform -> s_load
        const uint2 v = *(const uint2*)&fb[(size_t)mi*192 + co];
        a0 += bfhi2f(v.x << 16); a1 += bfhi2f(v.x & 0xffff0000u);
        a2 += bfhi2f(v.y << 16); a3 += bfhi2f(v.y & 0xffff0000u);
      }
      // elements e = 4*lane + j, e = d*3 + t; s_aggb row n=(g,t), col=d
      const float av0 = a0 * (1.f/KNB), av1 = a1 * (1.f/KNB);
      const float av2 = a2 * (1.f/KNB), av3 = a3 * (1.f/KNB);
      const int e = 4*lane;
      s_aggb[g*3 + ((e+0) % 3)][(e+0)/3] = f2bf(av0);
      s_aggb[g*3 + ((e+1) % 3)][(e+1)/3] = f2bf(av1);
      s_aggb[g*3 + ((e+2) % 3)][(e+2)/3] = f2bf(av2);
      s_aggb[g*3 + ((e+3) % 3)][(e+3)/3] = f2bf(av3);
    }
  } else {
    float s0 = 0.f, s1 = 0.f, s2 = 0.f;
    const int lofs = lane * 3;
#pragma unroll 8
    for (int k = 0; k < KNB; ++k) {
      const int mi = nbr[pu*KNB + k];                // wave-uniform -> s_load
      const float* fr = s_feats + (size_t)mi*(DDIM*3) + lofs;
      s0 += fr[0]; s1 += fr[1]; s2 += fr[2];
    }
    s_aggb[g*3+0][lane] = f2bf(s0 * (1.f/KNB));
    s_aggb[g*3+1][lane] = f2bf(s1 * (1.f/KNB));
    s_aggb[g*3+2][lane] = f2bf(s2 * (1.f/KNB));
  }

  __syncthreads();   // s_modb/s_aggb cross-wave; all s_h frag reads drained

  // ---- Gate via MFMA: rows = points (4 valid), cols = 192 outputs -----------
  {
    const bf16x8 am0 = *(const bf16x8*)&s_modb[ln][lq*8];
    const bf16x8 am1 = *(const bf16x8*)&s_modb[ln][lq*8 + 32];
#pragma unroll
    for (int t = 0; t < 3; ++t) {
      const int ot = g*3 + t;
      const bf16x8 bg0 = *(const bf16x8*)&wsu[WS_WG + (ot*2+0)*512 + lane*8];
      const bf16x8 bg1 = *(const bf16x8*)&wsu[WS_WG + (ot*2+1)*512 + lane*8];
      const float  bv  = bg[ln + 16*ot];
      f32x4 c = {bv, bv, bv, bv};
      c = __builtin_amdgcn_mfma_f32_16x16x32_bf16(am0, bg0, c, 0, 0, 0);
      c = __builtin_amdgcn_mfma_f32_16x16x32_bf16(am1, bg1, c, 0, 0, 0);
      if (lq == 0) {
#pragma unroll
        for (int r = 0; r < 4; ++r)
          s_gate[r][ln + 16*ot] = 1.f / (1.f + __expf(-c[r]));
      }
    }
  }

  // ---- Transform via MFMA: rows = outputs, cols = (point,t) -----------------
  {
    const bf16x8 ab0 = *(const bf16x8*)&s_aggb[ln][lq*8];
    const bf16x8 ab1 = *(const bf16x8*)&s_aggb[ln][lq*8 + 32];
    const int gi = ln / 3;            // valid for ln < 12
    const int tt = ln - gi*3;
#pragma unroll
    for (int t2 = 0; t2 < 3; ++t2) {
      const int ot = g*3 + t2;
      const bf16x8 av0 = *(const bf16x8*)&wsu[WS_WV + (ot*2+0)*512 + lane*8];
      const bf16x8 av1 = *(const bf16x8*)&wsu[WS_WV + (ot*2+1)*512 + lane*8];
      f32x4 c = {0.f, 0.f, 0.f, 0.f};
      c = __builtin_amdgcn_mfma_f32_16x16x32_bf16(av0, ab0, c, 0, 0, 0);
      c = __builtin_amdgcn_mfma_f32_16x16x32_bf16(av1, ab1, c, 0, 0, 0);
      if (ln < 12) {
#pragma unroll
        for (int r = 0; r < 4; ++r) {
          const int o = 16*ot + lq*4 + r;
          s_out[gi*592 + o*3 + tt] = c[r] * s_gate[gi][o];
        }
      }
    }
  }
  __syncthreads();

  // ---- Coalesced float4 output write ----------------------------------------
  {
    float4* outv = (float4*)out;
    const float4* sov = (const float4*)s_out;
#pragma unroll
    for (int i = 0; i < 3; ++i) {
      const int idx = tid + 256*i;
      if (idx < 576) {
        const int gg  = idx / 144;
        const int off = idx - gg*144;
        outv[(size_t)blockIdx.x * 576 + idx] = sov[gg*148 + off];
      }
    }
  }
}

extern "C" void kernel_launch(void* const* d_in, const int* in_sizes, int n_in,
                              void* d_out, int out_size, void* d_ws, size_t ws_size,
                              hipStream_t stream) {
  const float* q_pts   = (const float*)d_in[0];
  const float* s_pts   = (const float*)d_in[1];
  const float* s_feats = (const float*)d_in[2];
  const int*   nbr     = (const int*)  d_in[3];
  const float* normals = (const float*)d_in[4];
  const float* W1 = (const float*)d_in[5];
  const float* b1 = (const float*)d_in[6];
  const float* W2 = (const float*)d_in[7];
  const float* b2 = (const float*)d_in[8];
  const float* W3 = (const float*)d_in[9];
  const float* b3 = (const float*)d_in[10];
  const float* Wg = (const float*)d_in[11];
  const float* bg = (const float*)d_in[12];
  const float* Wv = (const float*)d_in[13];
  float* out = (float*)d_out;
  unsigned short* ws = (unsigned short*)d_ws;

  hipLaunchKernelGGL(prep_weights, dim3(68), dim3(64), 0, stream,
                     W1, W2, W3, Wg, Wv, ws);
  if (ws_size >= WS_NEED) {
    // 20000*192 floats / 8 per thread / 256 per block = 1875 blocks exactly
    hipLaunchKernelGGL(prep_feats, dim3(1875), dim3(256), 0, stream,
                       s_feats, ws + WS_FEATS);
    hipLaunchKernelGGL(ppf_fused<true>, dim3(NPTS / PPB), dim3(256), 0, stream,
                       q_pts, s_pts, s_feats, nbr, normals,
                       b1, b2, b3, bg, ws, out);
  } else {
    hipLaunchKernelGGL(ppf_fused<false>, dim3(NPTS / PPB), dim3(256), 0, stream,
                       q_pts, s_pts, s_feats, nbr, normals,
                       b1, b2, b3, bg, ws, out);
  }
}

// Round 8
// 158.477 us; speedup vs baseline: 1.6379x; 1.0031x over previous
//
#include <hip/hip_runtime.h>
#include <hip/hip_bf16.h>
#include <math.h>

#define NPTS 20000
#define KNB  32
#define DDIM 64
#define HIDN 64
#define OUTC 192
#define PPB  4

// d_ws layout, ushort units (bf16 MFMA fragments, 512 ushorts = 1 frag)
#define WS_W2 0        // 8 frags  (ct*2+ks)
#define WS_W3 4096     // 8 frags
#define WS_W1 8192     // 4 frags  (ct)
#define WS_WG 10240    // 24 frags (ot*2+ks)
#define WS_WV 22528    // 24 frags (ot*2+ks)
#define WS_FEATS 34816            // ushort offset of bf16 s_feats [M][192]
#define WS_NEED  (69632 + (size_t)NPTS*192*2)   // 7,749,632 bytes

typedef short bf16x8 __attribute__((ext_vector_type(8)));
typedef float f32x4  __attribute__((ext_vector_type(4)));

union BF8 { bf16x8 v; unsigned short us[8]; unsigned u[4]; };

__device__ __forceinline__ unsigned short f2bf(float f) {  // RNE, finite inputs
  unsigned u = __builtin_bit_cast(unsigned, f);
  u += 0x7fffu + ((u >> 16) & 1u);
  return (unsigned short)(u >> 16);
}
__device__ __forceinline__ float bfhi2f(unsigned hi) {     // hi = bf16 bits in [31:16]
  return __builtin_bit_cast(float, hi);
}
__device__ __forceinline__ unsigned pack2bf(float lo, float hi) {
  // v_cvt_pk_bf16_f32 on gfx950; low ushort = lo. (__hip_bfloat162 is not
  // trivially copyable -> bit_cast rejected; memcpy lowers to a reg move.)
  const __hip_bfloat162 h = __float22bfloat162_rn(make_float2(lo, hi));
  unsigned u;
  __builtin_memcpy(&u, &h, 4);
  return u;
}

__device__ __forceinline__ float fast_atan2pi(float y, float x) {
  // y >= 0; returns atan2(y,x)/pi; abs err ~1e-6
  const float ax = fabsf(x);
  const float mx = fmaxf(fmaxf(ax, y), 1e-30f);
  const float mn = fminf(ax, y);
  const float t  = mn * __builtin_amdgcn_rcpf(mx);
  const float s  = t * t;
  float p = -0.0117212f;
  p = fmaf(p, s,  0.05265332f);
  p = fmaf(p, s, -0.11643287f);
  p = fmaf(p, s,  0.19354346f);
  p = fmaf(p, s, -0.33262347f);
  p = fmaf(p, s,  0.99997726f);
  float r = p * t;
  if (y > ax)  r = 1.5707963268f - r;
  if (x < 0.f) r = 3.1415926536f - r;
  return r * 0.3183098862f;
}

__device__ __forceinline__ float angle3f(float ax, float ay, float az,
                                         float bx, float by, float bz) {
  const float y  = ax*bx + ay*by + az*bz;
  const float cx = ay*bz - az*by;
  const float cy = az*bx - ax*bz;
  const float cz = ax*by - ay*bx;
  const float xn = __builtin_amdgcn_sqrtf(cx*cx + cy*cy + cz*cz);
  return fast_atan2pi(xn, y);
}

// ---- prep: weights -> frag layout; feats -> bf16 [M][192]; one dispatch -----
// blocks 0..67: weight frags (64 threads used); blocks 68..1942: feats.
__global__ __launch_bounds__(256)
void prep_all(const float* __restrict__ sf,
              const float* __restrict__ W1, const float* __restrict__ W2,
              const float* __restrict__ W3, const float* __restrict__ Wg,
              const float* __restrict__ Wv, unsigned short* __restrict__ ws,
              int do_feats)
{
  const int b = blockIdx.x;
  if (b >= 68) {                       // feats: fp32 -> bf16, 8 floats/thread
    const int i = ((b - 68) * 256 + threadIdx.x) * 8;
    const float4 x = *(const float4*)&sf[i];
    const float4 y = *(const float4*)&sf[i + 4];
    uint4 w;
    w.x = f2bf(x.x) | ((unsigned)f2bf(x.y) << 16);
    w.y = f2bf(x.z) | ((unsigned)f2bf(x.w) << 16);
    w.z = f2bf(y.x) | ((unsigned)f2bf(y.y) << 16);
    w.w = f2bf(y.z) | ((unsigned)f2bf(y.w) << 16);
    *(uint4*)&ws[WS_FEATS + i] = w;
    return;
  }
  if (threadIdx.x >= 64) return;
  const int f  = b;                    // 68 weight frags
  const int L  = threadIdx.x;
  const int ln = L & 15, lq = L >> 4;
  unsigned short vals[8];
  if (f >= 16 && f < 20) {             // W1 [64][4], K padded to 32
    const int ct = f - 16;
#pragma unroll
    for (int j = 0; j < 8; ++j) {
      const float v = (lq == 0 && j < 4) ? W1[(ln + 16*ct)*4 + j] : 0.f;
      vals[j] = f2bf(v);
    }
  } else {
    const float* M; int q;
    if (f < 8)       { M = W2; q = f; }
    else if (f < 16) { M = W3; q = f - 8; }
    else if (f < 44) { M = Wg; q = f - 20; }
    else             { M = Wv; q = f - 44; }
    const int ct = q >> 1, ks = q & 1;
    const float* src = M + (ln + 16*ct)*64 + lq*8 + 32*ks;
#pragma unroll
    for (int j = 0; j < 8; ++j) vals[j] = f2bf(src[j]);
  }
  uint4 w;
  w.x = vals[0] | ((unsigned)vals[1] << 16);
  w.y = vals[2] | ((unsigned)vals[3] << 16);
  w.z = vals[4] | ((unsigned)vals[5] << 16);
  w.w = vals[6] | ((unsigned)vals[7] << 16);
  *(uint4*)&ws[f*512 + L*8] = w;
  (void)do_feats;
}

// ---- main fused kernel ------------------------------------------------------
// NOTE: no gather buffers live across phases, and no gather helper functions —
// address-taken buffers (r4 ptr arg, r5 lambda) defeat SROA -> scratch spill.
// Layers 1-2 use SWAPPED MFMA operands: mfma(W-frag, h-frag) -> D[channel][nbr],
// so a lane's 4 regs are 4 consecutive channels of one h-row -> packed b64 store.
template<bool BF>
__global__ __launch_bounds__(256, 6)
void ppf_fused(const float* __restrict__ q_pts,
               const float* __restrict__ s_pts,
               const float* __restrict__ s_feats,
               const int*   __restrict__ nbr,
               const float* __restrict__ normals,
               const float* __restrict__ b1, const float* __restrict__ b2,
               const float* __restrict__ b3, const float* __restrict__ bg,
               const unsigned short* __restrict__ wsu,
               float* __restrict__ out)
{
  // s_h rows: cols 0..63 = h tile (bf16); cols 64..71 = this row's ppf float4.
  __shared__ __align__(16) unsigned short s_h[PPB][KNB][72];   // 18432 B (alias s_out)
  __shared__ __align__(16) unsigned short s_modb[16][72];      //  2304 B
  __shared__ __align__(16) unsigned short s_aggb[16][72];      //  2304 B rows=(g,t)
  __shared__ float s_gate[PPB][200];                           //  3200 B
  float* s_out = (float*)&s_h[0][0][0];                        // 4 x 592 floats

  const int tid  = threadIdx.x;
  const int g    = tid >> 6;
  const int lane = tid & 63;
  const int lq   = lane >> 4;
  const int ln   = lane & 15;
  const int pu   = __builtin_amdgcn_readfirstlane(blockIdx.x * PPB + g);

  // ---- Phase A: PPF features, split across wave halves ----------------------
  {
    const float qx = q_pts[pu*3+0], qy = q_pts[pu*3+1], qz = q_pts[pu*3+2];
    const int   i0 = nbr[pu*KNB];
    const float qnx = normals[i0*3+0], qny = normals[i0*3+1], qnz = normals[i0*3+2];
    const int k  = lane & 31;
    const int mi = nbr[pu*KNB + k];
    const float px = s_pts[mi*3+0], py = s_pts[mi*3+1], pz = s_pts[mi*3+2];
    const float nx = normals[mi*3+0], ny = normals[mi*3+1], nz = normals[mi*3+2];
    const float vx = px - qx, vy = py - qy, vz = pz - qz;
    float* ppfrow = (float*)&s_h[g][k][64];
    if (lane < KNB) {
      ppfrow[1] = angle3f(qnx,qny,qnz, vx,vy,vz);
      ppfrow[2] = angle3f(nx,ny,nz,    vx,vy,vz);
    } else {
      ppfrow[0] = __builtin_amdgcn_sqrtf(vx*vx + vy*vy + vz*vz);
      ppfrow[3] = angle3f(qnx,qny,qnz, nx,ny,nz);
    }
  }
  // ppf produced/consumed by the same wave; per-wave DS ops are in order.

  // ---- Layer 1 (swapped): relu(W1 @ ppf^T + b1) -> packed h rows ------------
  {
    BF8 pf[2];
    pf[0].u[0]=pf[0].u[1]=pf[0].u[2]=pf[0].u[3]=0;
    pf[1] = pf[0];
    if (lq == 0) {
#pragma unroll
      for (int rt = 0; rt < 2; ++rt) {
        const float4 pv = *(const float4*)&s_h[g][ln + 16*rt][64];
        pf[rt].us[0]=f2bf(pv.x); pf[rt].us[1]=f2bf(pv.y);
        pf[rt].us[2]=f2bf(pv.z); pf[rt].us[3]=f2bf(pv.w);
      }
    }
#pragma unroll
    for (int ct = 0; ct < 4; ++ct) {
      const bf16x8 aw  = *(const bf16x8*)&wsu[WS_W1 + ct*512 + lane*8];
      const float4 bv4 = *(const float4*)&b1[ct*16 + lq*4];
#pragma unroll
      for (int rt = 0; rt < 2; ++rt) {
        f32x4 c = {bv4.x, bv4.y, bv4.z, bv4.w};
        c = __builtin_amdgcn_mfma_f32_16x16x32_bf16(aw, pf[rt].v, c, 0, 0, 0);
        uint2 pk;
        pk.x = pack2bf(fmaxf(c[0], 0.f), fmaxf(c[1], 0.f));
        pk.y = pack2bf(fmaxf(c[2], 0.f), fmaxf(c[3], 0.f));
        *(uint2*)&s_h[g][ln + 16*rt][ct*16 + lq*4] = pk;   // row=nbr, 4 channels
      }
    }
  }

  // ---- Layer 2 (swapped): relu(W2 @ h1^T + b2), in place --------------------
  // (in-place safe: the wave's 4 A-frag ds_reads precede all its ds_writes)
  {
    bf16x8 wf[8];
#pragma unroll
    for (int fIdx = 0; fIdx < 8; ++fIdx)
      wf[fIdx] = *(const bf16x8*)&wsu[WS_W2 + fIdx*512 + lane*8];
    bf16x8 hf[4];
#pragma unroll
    for (int rt = 0; rt < 2; ++rt)
#pragma unroll
      for (int ks = 0; ks < 2; ++ks)
        hf[rt*2+ks] = *(const bf16x8*)&s_h[g][ln + 16*rt][lq*8 + ks*32];
#pragma unroll
    for (int ct = 0; ct < 4; ++ct) {
      const float4 bv4 = *(const float4*)&b2[ct*16 + lq*4];
#pragma unroll
      for (int rt = 0; rt < 2; ++rt) {
        f32x4 c = {bv4.x, bv4.y, bv4.z, bv4.w};
        c = __builtin_amdgcn_mfma_f32_16x16x32_bf16(wf[ct*2+0], hf[rt*2+0], c, 0, 0, 0);
        c = __builtin_amdgcn_mfma_f32_16x16x32_bf16(wf[ct*2+1], hf[rt*2+1], c, 0, 0, 0);
        uint2 pk;
        pk.x = pack2bf(fmaxf(c[0], 0.f), fmaxf(c[1], 0.f));
        pk.y = pack2bf(fmaxf(c[2], 0.f), fmaxf(c[3], 0.f));
        *(uint2*)&s_h[g][ln + 16*rt][ct*16 + lq*4] = pk;
      }
    }
  }

  // ---- Layer 3 (unswapped) + fused mean over K -> s_modb --------------------
  {
    bf16x8 wf[8];
#pragma unroll
    for (int fIdx = 0; fIdx < 8; ++fIdx)
      wf[fIdx] = *(const bf16x8*)&wsu[WS_W3 + fIdx*512 + lane*8];
    bf16x8 af[4];
#pragma unroll
    for (int rt = 0; rt < 2; ++rt)
#pragma unroll
      for (int ks = 0; ks < 2; ++ks)
        af[rt*2+ks] = *(const bf16x8*)&s_h[g][ln + 16*rt][lq*8 + ks*32];
#pragma unroll
    for (int ct = 0; ct < 4; ++ct) {
      const float bv = b3[ln + 16*ct];
      f32x4 c0 = {bv, bv, bv, bv};
      c0 = __builtin_amdgcn_mfma_f32_16x16x32_bf16(af[0], wf[ct*2+0], c0, 0, 0, 0);
      c0 = __builtin_amdgcn_mfma_f32_16x16x32_bf16(af[1], wf[ct*2+1], c0, 0, 0, 0);
      f32x4 c1 = {bv, bv, bv, bv};
      c1 = __builtin_amdgcn_mfma_f32_16x16x32_bf16(af[2], wf[ct*2+0], c1, 0, 0, 0);
      c1 = __builtin_amdgcn_mfma_f32_16x16x32_bf16(af[3], wf[ct*2+1], c1, 0, 0, 0);
      float s = (c0[0]+c0[1]+c0[2]+c0[3]) + (c1[0]+c1[1]+c1[2]+c1[3]);
      s += __shfl_xor(s, 16);
      s += __shfl_xor(s, 32);
      if (lq == 0) s_modb[g][ln + 16*ct] = f2bf(s * (1.f/KNB));
    }
  }

  // ---- Neighbor-feature mean (inline loop; latency hidden by other waves) ---
  if constexpr (BF) {
    if (lane < 48) {
      float a0 = 0.f, a1 = 0.f, a2 = 0.f, a3 = 0.f;
      const unsigned short* fb = wsu + WS_FEATS;
      const int co = lane * 4;
#pragma unroll 8
      for (int k = 0; k < KNB; ++k) {
        const int mi = nbr[pu*KNB + k];              // wave-uniform -> s_load
        const uint2 v = *(const uint2*)&fb[(size_t)mi*192 + co];
        a0 += bfhi2f(v.x << 16); a1 += bfhi2f(v.x & 0xffff0000u);
        a2 += bfhi2f(v.y << 16); a3 += bfhi2f(v.y & 0xffff0000u);
      }
      // elements e = 4*lane + j, e = d*3 + t; s_aggb row n=(g,t), col=d
      const float av0 = a0 * (1.f/KNB), av1 = a1 * (1.f/KNB);
      const float av2 = a2 * (1.f/KNB), av3 = a3 * (1.f/KNB);
      const int e = 4*lane;
      s_aggb[g*3 + ((e+0) % 3)][(e+0)/3] = f2bf(av0);
      s_aggb[g*3 + ((e+1) % 3)][(e+1)/3] = f2bf(av1);
      s_aggb[g*3 + ((e+2) % 3)][(e+2)/3] = f2bf(av2);
      s_aggb[g*3 + ((e+3) % 3)][(e+3)/3] = f2bf(av3);
    }
  } else {
    float s0 = 0.f, s1 = 0.f, s2 = 0.f;
    const int lofs = lane * 3;
#pragma unroll 8
    for (int k = 0; k < KNB; ++k) {
      const int mi = nbr[pu*KNB + k];                // wave-uniform -> s_load
      const float* fr = s_feats + (size_t)mi*(DDIM*3) + lofs;
      s0 += fr[0]; s1 += fr[1]; s2 += fr[2];
    }
    s_aggb[g*3+0][lane] = f2bf(s0 * (1.f/KNB));
    s_aggb[g*3+1][lane] = f2bf(s1 * (1.f/KNB));
    s_aggb[g*3+2][lane] = f2bf(s2 * (1.f/KNB));
  }

  __syncthreads();   // s_modb/s_aggb cross-wave; all s_h frag reads drained

  // ---- Gate via MFMA: rows = points (4 valid), cols = 192 outputs -----------
  {
    const bf16x8 am0 = *(const bf16x8*)&s_modb[ln][lq*8];
    const bf16x8 am1 = *(const bf16x8*)&s_modb[ln][lq*8 + 32];
#pragma unroll
    for (int t = 0; t < 3; ++t) {
      const int ot = g*3 + t;
      const bf16x8 bg0 = *(const bf16x8*)&wsu[WS_WG + (ot*2+0)*512 + lane*8];
      const bf16x8 bg1 = *(const bf16x8*)&wsu[WS_WG + (ot*2+1)*512 + lane*8];
      const float  bv  = bg[ln + 16*ot];
      f32x4 c = {bv, bv, bv, bv};
      c = __builtin_amdgcn_mfma_f32_16x16x32_bf16(am0, bg0, c, 0, 0, 0);
      c = __builtin_amdgcn_mfma_f32_16x16x32_bf16(am1, bg1, c, 0, 0, 0);
      if (lq == 0) {
#pragma unroll
        for (int r = 0; r < 4; ++r)
          s_gate[r][ln + 16*ot] = 1.f / (1.f + __expf(-c[r]));
      }
    }
  }

  // ---- Transform via MFMA: rows = outputs, cols = (point,t) -----------------
  {
    const bf16x8 ab0 = *(const bf16x8*)&s_aggb[ln][lq*8];
    const bf16x8 ab1 = *(const bf16x8*)&s_aggb[ln][lq*8 + 32];
    const int gi = ln / 3;            // valid for ln < 12
    const int tt = ln - gi*3;
#pragma unroll
    for (int t2 = 0; t2 < 3; ++t2) {
      const int ot = g*3 + t2;
      const bf16x8 av0 = *(const bf16x8*)&wsu[WS_WV + (ot*2+0)*512 + lane*8];
      const bf16x8 av1 = *(const bf16x8*)&wsu[WS_WV + (ot*2+1)*512 + lane*8];
      f32x4 c = {0.f, 0.f, 0.f, 0.f};
      c = __builtin_amdgcn_mfma_f32_16x16x32_bf16(av0, ab0, c, 0, 0, 0);
      c = __builtin_amdgcn_mfma_f32_16x16x32_bf16(av1, ab1, c, 0, 0, 0);
      if (ln < 12) {
#pragma unroll
        for (int r = 0; r < 4; ++r) {
          const int o = 16*ot + lq*4 + r;
          s_out[gi*592 + o*3 + tt] = c[r] * s_gate[gi][o];
        }
      }
    }
  }
  __syncthreads();

  // ---- Coalesced float4 output write ----------------------------------------
  {
    float4* outv = (float4*)out;
    const float4* sov = (const float4*)s_out;
#pragma unroll
    for (int i = 0; i < 3; ++i) {
      const int idx = tid + 256*i;
      if (idx < 576) {
        const int gg  = idx / 144;
        const int off = idx - gg*144;
        outv[(size_t)blockIdx.x * 576 + idx] = sov[gg*148 + off];
      }
    }
  }
}

extern "C" void kernel_launch(void* const* d_in, const int* in_sizes, int n_in,
                              void* d_out, int out_size, void* d_ws, size_t ws_size,
                              hipStream_t stream) {
  const float* q_pts   = (const float*)d_in[0];
  const float* s_pts   = (const float*)d_in[1];
  const float* s_feats = (const float*)d_in[2];
  const int*   nbr     = (const int*)  d_in[3];
  const float* normals = (const float*)d_in[4];
  const float* W1 = (const float*)d_in[5];
  const float* b1 = (const float*)d_in[6];
  const float* W2 = (const float*)d_in[7];
  const float* b2 = (const float*)d_in[8];
  const float* W3 = (const float*)d_in[9];
  const float* b3 = (const float*)d_in[10];
  const float* Wg = (const float*)d_in[11];
  const float* bg = (const float*)d_in[12];
  const float* Wv = (const float*)d_in[13];
  float* out = (float*)d_out;
  unsigned short* ws = (unsigned short*)d_ws;

  const int do_feats = (ws_size >= WS_NEED) ? 1 : 0;
  // feats: 20000*192 floats / 8 per thread / 256 per block = 1875 blocks
  const int prep_blocks = do_feats ? (68 + 1875) : 68;
  hipLaunchKernelGGL(prep_all, dim3(prep_blocks), dim3(256), 0, stream,
                     s_feats, W1, W2, W3, Wg, Wv, ws, do_feats);
  if (do_feats) {
    hipLaunchKernelGGL(ppf_fused<true>, dim3(NPTS / PPB), dim3(256), 0, stream,
                       q_pts, s_pts, s_feats, nbr, normals,
                       b1, b2, b3, bg, ws, out);
  } else {
    hipLaunchKernelGGL(ppf_fused<false>, dim3(NPTS / PPB), dim3(256), 0, stream,
                       q_pts, s_pts, s_feats, nbr, normals,
                       b1, b2, b3, bg, ws, out);
  }
}

// Round 9
// 158.309 us; speedup vs baseline: 1.6396x; 1.0011x over previous
//
#include <hip/hip_runtime.h>
#include <hip/hip_bf16.h>
#include <math.h>

#define NPTS 20000
#define KNB  32
#define DDIM 64
#define HIDN 64
#define OUTC 192
#define PPB  4

// d_ws layout, ushort units (bf16 MFMA fragments, 512 ushorts = 1 frag)
#define WS_W2 0        // 8 frags  (ct*2+ks)
#define WS_W3 4096     // 8 frags
#define WS_W1 8192     // 4 frags  (ct) -- K-cols permuted to (a1,a2,d,a3)
#define WS_WG 10240    // 24 frags (ot*2+ks)
#define WS_WV 22528    // 24 frags (ot*2+ks)
#define WS_FEATS 34816            // ushort offset of bf16 s_feats [M][192]
#define WS_NEED  (69632 + (size_t)NPTS*192*2)   // 7,749,632 bytes

typedef short bf16x8 __attribute__((ext_vector_type(8)));
typedef float f32x4  __attribute__((ext_vector_type(4)));

union BF8 { bf16x8 v; unsigned short us[8]; unsigned u[4]; };

__device__ __forceinline__ unsigned short f2bf(float f) {  // RNE, finite inputs
  unsigned u = __builtin_bit_cast(unsigned, f);
  u += 0x7fffu + ((u >> 16) & 1u);
  return (unsigned short)(u >> 16);
}
__device__ __forceinline__ float bfhi2f(unsigned hi) {     // hi = bf16 bits in [31:16]
  return __builtin_bit_cast(float, hi);
}
__device__ __forceinline__ unsigned pack2bf(float lo, float hi) {
  // v_cvt_pk_bf16_f32 on gfx950; low ushort = lo. (__hip_bfloat162 is not
  // trivially copyable -> bit_cast rejected; memcpy lowers to a reg move.)
  const __hip_bfloat162 h = __float22bfloat162_rn(make_float2(lo, hi));
  unsigned u;
  __builtin_memcpy(&u, &h, 4);
  return u;
}

__device__ __forceinline__ float fast_atan2pi(float y, float x) {
  // y >= 0; returns atan2(y,x)/pi; abs err ~1e-6
  const float ax = fabsf(x);
  const float mx = fmaxf(fmaxf(ax, y), 1e-30f);
  const float mn = fminf(ax, y);
  const float t  = mn * __builtin_amdgcn_rcpf(mx);
  const float s  = t * t;
  float p = -0.0117212f;
  p = fmaf(p, s,  0.05265332f);
  p = fmaf(p, s, -0.11643287f);
  p = fmaf(p, s,  0.19354346f);
  p = fmaf(p, s, -0.33262347f);
  p = fmaf(p, s,  0.99997726f);
  float r = p * t;
  if (y > ax)  r = 1.5707963268f - r;
  if (x < 0.f) r = 3.1415926536f - r;
  return r * 0.3183098862f;
}

__device__ __forceinline__ float angle3f(float ax, float ay, float az,
                                         float bx, float by, float bz) {
  const float y  = ax*bx + ay*by + az*bz;
  const float cx = ay*bz - az*by;
  const float cy = az*bx - ax*bz;
  const float cz = ax*by - ay*bx;
  const float xn = __builtin_amdgcn_sqrtf(cx*cx + cy*cy + cz*cz);
  return fast_atan2pi(xn, y);
}

// ---- prep: weights -> frag layout; feats -> bf16 [M][192]; one dispatch -----
// blocks 0..67: weight frags (64 threads used); blocks 68..1942: feats.
__global__ __launch_bounds__(256)
void prep_all(const float* __restrict__ sf,
              const float* __restrict__ W1, const float* __restrict__ W2,
              const float* __restrict__ W3, const float* __restrict__ Wg,
              const float* __restrict__ Wv, unsigned short* __restrict__ ws,
              int do_feats)
{
  const int b = blockIdx.x;
  if (b >= 68) {                       // feats: fp32 -> bf16, 8 floats/thread
    const int i = ((b - 68) * 256 + threadIdx.x) * 8;
    const float4 x = *(const float4*)&sf[i];
    const float4 y = *(const float4*)&sf[i + 4];
    uint4 w;
    w.x = f2bf(x.x) | ((unsigned)f2bf(x.y) << 16);
    w.y = f2bf(x.z) | ((unsigned)f2bf(x.w) << 16);
    w.z = f2bf(y.x) | ((unsigned)f2bf(y.y) << 16);
    w.w = f2bf(y.z) | ((unsigned)f2bf(y.w) << 16);
    *(uint4*)&ws[WS_FEATS + i] = w;
    return;
  }
  if (threadIdx.x >= 64) return;
  const int f  = b;                    // 68 weight frags
  const int L  = threadIdx.x;
  const int ln = L & 15, lq = L >> 4;
  unsigned short vals[8];
  if (f >= 16 && f < 20) {             // W1 [64][4]; K permuted (a1,a2,d,a3), pad 32
    const int ct = f - 16;
    const int perm[4] = {1, 2, 0, 3};  // ppf stored as (a1,a2,d,a3) in LDS
#pragma unroll
    for (int j = 0; j < 8; ++j) {
      const float v = (lq == 0 && j < 4) ? W1[(ln + 16*ct)*4 + perm[j]] : 0.f;
      vals[j] = f2bf(v);
    }
  } else {
    const float* M; int q;
    if (f < 8)       { M = W2; q = f; }
    else if (f < 16) { M = W3; q = f - 8; }
    else if (f < 44) { M = Wg; q = f - 20; }
    else             { M = Wv; q = f - 44; }
    const int ct = q >> 1, ks = q & 1;
    const float* src = M + (ln + 16*ct)*64 + lq*8 + 32*ks;
#pragma unroll
    for (int j = 0; j < 8; ++j) vals[j] = f2bf(src[j]);
  }
  uint4 w;
  w.x = vals[0] | ((unsigned)vals[1] << 16);
  w.y = vals[2] | ((unsigned)vals[3] << 16);
  w.z = vals[4] | ((unsigned)vals[5] << 16);
  w.w = vals[6] | ((unsigned)vals[7] << 16);
  *(uint4*)&ws[f*512 + L*8] = w;
  (void)do_feats;
}

// ---- main fused kernel ------------------------------------------------------
// NOTE: no gather buffers live across phases, and no gather helper functions —
// address-taken buffers (r4 ptr arg, r5 lambda) defeat SROA -> scratch spill.
// Layers 1-2 use SWAPPED MFMA operands: mfma(W-frag, h-frag) -> D[channel][nbr],
// so a lane's 4 regs are 4 consecutive channels of one h-row -> packed b64 store.
// LDS budget 21,760 B -> 7 blocks/CU (r8 was 26,624 -> 6): ppf stored bf16,
// row stride 72->68, gate stored bf16 aliased into s_modb rows 4..15 (those
// rows are only ever read as discarded garbage rows of the gate A-frag).
template<bool BF>
__global__ __launch_bounds__(256, 7)
void ppf_fused(const float* __restrict__ q_pts,
               const float* __restrict__ s_pts,
               const float* __restrict__ s_feats,
               const int*   __restrict__ nbr,
               const float* __restrict__ normals,
               const float* __restrict__ b1, const float* __restrict__ b2,
               const float* __restrict__ b3, const float* __restrict__ bg,
               const unsigned short* __restrict__ wsu,
               float* __restrict__ out)
{
  // s_h rows: cols 0..63 = h tile (bf16); cols 64..67 = ppf (a1,a2,d,a3) bf16.
  __shared__ __align__(16) unsigned short s_h[PPB][KNB][68];   // 17408 B (alias s_out)
  __shared__ __align__(16) unsigned short s_modb[16][68];      //  2176 B; rows 4..15 = gate
  __shared__ __align__(16) unsigned short s_aggb[16][68];      //  2176 B rows=(g,t)
  float* s_out = (float*)&s_h[0][0][0];                        // 4 x 592 floats
  unsigned short* s_gateb = &s_modb[4][0];                     // 768 of 816 ushorts

  const int tid  = threadIdx.x;
  const int g    = tid >> 6;
  const int lane = tid & 63;
  const int lq   = lane >> 4;
  const int ln   = lane & 15;
  const int pu   = __builtin_amdgcn_readfirstlane(blockIdx.x * PPB + g);

  // ---- Phase A: PPF features, split across wave halves ----------------------
  {
    const float qx = q_pts[pu*3+0], qy = q_pts[pu*3+1], qz = q_pts[pu*3+2];
    const int   i0 = nbr[pu*KNB];
    const float qnx = normals[i0*3+0], qny = normals[i0*3+1], qnz = normals[i0*3+2];
    const int k  = lane & 31;
    const int mi = nbr[pu*KNB + k];
    const float px = s_pts[mi*3+0], py = s_pts[mi*3+1], pz = s_pts[mi*3+2];
    const float nx = normals[mi*3+0], ny = normals[mi*3+1], nz = normals[mi*3+2];
    const float vx = px - qx, vy = py - qy, vz = pz - qz;
    unsigned* pp = (unsigned*)&s_h[g][k][64];
    if (lane < KNB) {
      const float a1v = angle3f(qnx,qny,qnz, vx,vy,vz);
      const float a2v = angle3f(nx,ny,nz,    vx,vy,vz);
      pp[0] = pack2bf(a1v, a2v);
    } else {
      const float dv  = __builtin_amdgcn_sqrtf(vx*vx + vy*vy + vz*vz);
      const float a3v = angle3f(qnx,qny,qnz, nx,ny,nz);
      pp[1] = pack2bf(dv, a3v);
    }
  }
  // ppf produced/consumed by the same wave; per-wave DS ops are in order.

  // ---- Layer 1 (swapped): relu(W1 @ ppf^T + b1) -> packed h rows ------------
  {
    BF8 pf[2];
    pf[0].u[0]=pf[0].u[1]=pf[0].u[2]=pf[0].u[3]=0;
    pf[1] = pf[0];
    if (lq == 0) {
#pragma unroll
      for (int rt = 0; rt < 2; ++rt) {
        const uint2 pv = *(const uint2*)&s_h[g][ln + 16*rt][64];
        pf[rt].u[0] = pv.x; pf[rt].u[1] = pv.y;   // (a1,a2,d,a3) bf16, k 4..31 = 0
      }
    }
#pragma unroll
    for (int ct = 0; ct < 4; ++ct) {
      const bf16x8 aw  = *(const bf16x8*)&wsu[WS_W1 + ct*512 + lane*8];
      const float4 bv4 = *(const float4*)&b1[ct*16 + lq*4];
#pragma unroll
      for (int rt = 0; rt < 2; ++rt) {
        f32x4 c = {bv4.x, bv4.y, bv4.z, bv4.w};
        c = __builtin_amdgcn_mfma_f32_16x16x32_bf16(aw, pf[rt].v, c, 0, 0, 0);
        uint2 pk;
        pk.x = pack2bf(fmaxf(c[0], 0.f), fmaxf(c[1], 0.f));
        pk.y = pack2bf(fmaxf(c[2], 0.f), fmaxf(c[3], 0.f));
        *(uint2*)&s_h[g][ln + 16*rt][ct*16 + lq*4] = pk;   // row=nbr, 4 channels
      }
    }
  }

  // ---- Layer 2 (swapped): relu(W2 @ h1^T + b2), in place --------------------
  // (in-place safe: the wave's 4 A-frag ds_reads precede all its ds_writes)
  {
    bf16x8 wf[8];
#pragma unroll
    for (int fIdx = 0; fIdx < 8; ++fIdx)
      wf[fIdx] = *(const bf16x8*)&wsu[WS_W2 + fIdx*512 + lane*8];
    bf16x8 hf[4];
#pragma unroll
    for (int rt = 0; rt < 2; ++rt)
#pragma unroll
      for (int ks = 0; ks < 2; ++ks)
        hf[rt*2+ks] = *(const bf16x8*)&s_h[g][ln + 16*rt][lq*8 + ks*32];
#pragma unroll
    for (int ct = 0; ct < 4; ++ct) {
      const float4 bv4 = *(const float4*)&b2[ct*16 + lq*4];
#pragma unroll
      for (int rt = 0; rt < 2; ++rt) {
        f32x4 c = {bv4.x, bv4.y, bv4.z, bv4.w};
        c = __builtin_amdgcn_mfma_f32_16x16x32_bf16(wf[ct*2+0], hf[rt*2+0], c, 0, 0, 0);
        c = __builtin_amdgcn_mfma_f32_16x16x32_bf16(wf[ct*2+1], hf[rt*2+1], c, 0, 0, 0);
        uint2 pk;
        pk.x = pack2bf(fmaxf(c[0], 0.f), fmaxf(c[1], 0.f));
        pk.y = pack2bf(fmaxf(c[2], 0.f), fmaxf(c[3], 0.f));
        *(uint2*)&s_h[g][ln + 16*rt][ct*16 + lq*4] = pk;
      }
    }
  }

  // ---- Layer 3 (unswapped) + fused mean over K -> s_modb --------------------
  {
    bf16x8 wf[8];
#pragma unroll
    for (int fIdx = 0; fIdx < 8; ++fIdx)
      wf[fIdx] = *(const bf16x8*)&wsu[WS_W3 + fIdx*512 + lane*8];
    bf16x8 af[4];
#pragma unroll
    for (int rt = 0; rt < 2; ++rt)
#pragma unroll
      for (int ks = 0; ks < 2; ++ks)
        af[rt*2+ks] = *(const bf16x8*)&s_h[g][ln + 16*rt][lq*8 + ks*32];
#pragma unroll
    for (int ct = 0; ct < 4; ++ct) {
      const float bv = b3[ln + 16*ct];
      f32x4 c0 = {bv, bv, bv, bv};
      c0 = __builtin_amdgcn_mfma_f32_16x16x32_bf16(af[0], wf[ct*2+0], c0, 0, 0, 0);
      c0 = __builtin_amdgcn_mfma_f32_16x16x32_bf16(af[1], wf[ct*2+1], c0, 0, 0, 0);
      f32x4 c1 = {bv, bv, bv, bv};
      c1 = __builtin_amdgcn_mfma_f32_16x16x32_bf16(af[2], wf[ct*2+0], c1, 0, 0, 0);
      c1 = __builtin_amdgcn_mfma_f32_16x16x32_bf16(af[3], wf[ct*2+1], c1, 0, 0, 0);
      float s = (c0[0]+c0[1]+c0[2]+c0[3]) + (c1[0]+c1[1]+c1[2]+c1[3]);
      s += __shfl_xor(s, 16);
      s += __shfl_xor(s, 32);
      if (lq == 0) s_modb[g][ln + 16*ct] = f2bf(s * (1.f/KNB));
    }
  }

  // ---- Neighbor-feature mean (inline loop; latency hidden by other waves) ---
  if constexpr (BF) {
    if (lane < 48) {
      float a0 = 0.f, a1 = 0.f, a2 = 0.f, a3 = 0.f;
      const unsigned short* fb = wsu + WS_FEATS;
      const int co = lane * 4;
#pragma unroll 8
      for (int k = 0; k < KNB; ++k) {
        const int mi = nbr[pu*KNB + k];              // wave-uniform -> s_load
        const uint2 v = *(const uint2*)&fb[(size_t)mi*192 + co];
        a0 += bfhi2f(v.x << 16); a1 += bfhi2f(v.x & 0xffff0000u);
        a2 += bfhi2f(v.y << 16); a3 += bfhi2f(v.y & 0xffff0000u);
      }
      // elements e = 4*lane + j, e = d*3 + t; s_aggb row n=(g,t), col=d
      const float av0 = a0 * (1.f/KNB), av1 = a1 * (1.f/KNB);
      const float av2 = a2 * (1.f/KNB), av3 = a3 * (1.f/KNB);
      const int e = 4*lane;
      s_aggb[g*3 + ((e+0) % 3)][(e+0)/3] = f2bf(av0);
      s_aggb[g*3 + ((e+1) % 3)][(e+1)/3] = f2bf(av1);
      s_aggb[g*3 + ((e+2) % 3)][(e+2)/3] = f2bf(av2);
      s_aggb[g*3 + ((e+3) % 3)][(e+3)/3] = f2bf(av3);
    }
  } else {
    float s0 = 0.f, s1 = 0.f, s2 = 0.f;
    const int lofs = lane * 3;
#pragma unroll 8
    for (int k = 0; k < KNB; ++k) {
      const int mi = nbr[pu*KNB + k];                // wave-uniform -> s_load
      const float* fr = s_feats + (size_t)mi*(DDIM*3) + lofs;
      s0 += fr[0]; s1 += fr[1]; s2 += fr[2];
    }
    s_aggb[g*3+0][lane] = f2bf(s0 * (1.f/KNB));
    s_aggb[g*3+1][lane] = f2bf(s1 * (1.f/KNB));
    s_aggb[g*3+2][lane] = f2bf(s2 * (1.f/KNB));
  }

  __syncthreads();   // s_modb/s_aggb cross-wave; all s_h frag reads drained

  // ---- Gate via MFMA: rows = points (4 valid), cols = 192 outputs -----------
  // A-frag rows 4..15 are garbage (incl. other waves' gate bits) — D rows 4..15
  // are discarded; matmul row independence makes this safe.
  {
    const bf16x8 am0 = *(const bf16x8*)&s_modb[ln][lq*8];
    const bf16x8 am1 = *(const bf16x8*)&s_modb[ln][lq*8 + 32];
#pragma unroll
    for (int t = 0; t < 3; ++t) {
      const int ot = g*3 + t;
      const bf16x8 bg0 = *(const bf16x8*)&wsu[WS_WG + (ot*2+0)*512 + lane*8];
      const bf16x8 bg1 = *(const bf16x8*)&wsu[WS_WG + (ot*2+1)*512 + lane*8];
      const float  bv  = bg[ln + 16*ot];
      f32x4 c = {bv, bv, bv, bv};
      c = __builtin_amdgcn_mfma_f32_16x16x32_bf16(am0, bg0, c, 0, 0, 0);
      c = __builtin_amdgcn_mfma_f32_16x16x32_bf16(am1, bg1, c, 0, 0, 0);
      if (lq == 0) {
#pragma unroll
        for (int r = 0; r < 4; ++r)    // gate cols are per-wave partitioned
          s_gateb[r*192 + ln + 16*ot] = f2bf(1.f / (1.f + __expf(-c[r])));
      }
    }
  }

  // ---- Transform via MFMA: rows = outputs, cols = (point,t) -----------------
  {
    const bf16x8 ab0 = *(const bf16x8*)&s_aggb[ln][lq*8];
    const bf16x8 ab1 = *(const bf16x8*)&s_aggb[ln][lq*8 + 32];
    const int gi = ln / 3;            // valid for ln < 12
    const int tt = ln - gi*3;
#pragma unroll
    for (int t2 = 0; t2 < 3; ++t2) {
      const int ot = g*3 + t2;
      const bf16x8 av0 = *(const bf16x8*)&wsu[WS_WV + (ot*2+0)*512 + lane*8];
      const bf16x8 av1 = *(const bf16x8*)&wsu[WS_WV + (ot*2+1)*512 + lane*8];
      f32x4 c = {0.f, 0.f, 0.f, 0.f};
      c = __builtin_amdgcn_mfma_f32_16x16x32_bf16(av0, ab0, c, 0, 0, 0);
      c = __builtin_amdgcn_mfma_f32_16x16x32_bf16(av1, ab1, c, 0, 0, 0);
      if (ln < 12) {
#pragma unroll
        for (int r = 0; r < 4; ++r) {
          const int o = 16*ot + lq*4 + r;          // own col partition only
          const float gt = bfhi2f(((unsigned)s_gateb[gi*192 + o]) << 16);
          s_out[gi*592 + o*3 + tt] = c[r] * gt;
        }
      }
    }
  }
  __syncthreads();

  // ---- Coalesced float4 output write ----------------------------------------
  {
    float4* outv = (float4*)out;
    const float4* sov = (const float4*)s_out;
#pragma unroll
    for (int i = 0; i < 3; ++i) {
      const int idx = tid + 256*i;
      if (idx < 576) {
        const int gg  = idx / 144;
        const int off = idx - gg*144;
        outv[(size_t)blockIdx.x * 576 + idx] = sov[gg*148 + off];
      }
    }
  }
}

extern "C" void kernel_launch(void* const* d_in, const int* in_sizes, int n_in,
                              void* d_out, int out_size, void* d_ws, size_t ws_size,
                              hipStream_t stream) {
  const float* q_pts   = (const float*)d_in[0];
  const float* s_pts   = (const float*)d_in[1];
  const float* s_feats = (const float*)d_in[2];
  const int*   nbr     = (const int*)  d_in[3];
  const float* normals = (const float*)d_in[4];
  const float* W1 = (const float*)d_in[5];
  const float* b1 = (const float*)d_in[6];
  const float* W2 = (const float*)d_in[7];
  const float* b2 = (const float*)d_in[8];
  const float* W3 = (const float*)d_in[9];
  const float* b3 = (const float*)d_in[10];
  const float* Wg = (const float*)d_in[11];
  const float* bg = (const float*)d_in[12];
  const float* Wv = (const float*)d_in[13];
  float* out = (float*)d_out;
  unsigned short* ws = (unsigned short*)d_ws;

  const int do_feats = (ws_size >= WS_NEED) ? 1 : 0;
  // feats: 20000*192 floats / 8 per thread / 256 per block = 1875 blocks
  const int prep_blocks = do_feats ? (68 + 1875) : 68;
  hipLaunchKernelGGL(prep_all, dim3(prep_blocks), dim3(256), 0, stream,
                     s_feats, W1, W2, W3, Wg, Wv, ws, do_feats);
  if (do_feats) {
    hipLaunchKernelGGL(ppf_fused<true>, dim3(NPTS / PPB), dim3(256), 0, stream,
                       q_pts, s_pts, s_feats, nbr, normals,
                       b1, b2, b3, bg, ws, out);
  } else {
    hipLaunchKernelGGL(ppf_fused<false>, dim3(NPTS / PPB), dim3(256), 0, stream,
                       q_pts, s_pts, s_feats, nbr, normals,
                       b1, b2, b3, bg, ws, out);
  }
}

// Round 10
// 158.166 us; speedup vs baseline: 1.6411x; 1.0009x over previous
//
#include <hip/hip_runtime.h>
#include <hip/hip_bf16.h>
#include <math.h>

#define NPTS 20000
#define KNB  32
#define DDIM 64
#define HIDN 64
#define OUTC 192
#define PPB  4

// d_ws layout, ushort units (bf16 MFMA fragments, 512 ushorts = 1 frag)
#define WS_W2 0        // 8 frags  (ct*2+ks)
#define WS_W3 4096     // 8 frags
#define WS_W1 8192     // 4 frags  (ct) -- K-cols permuted to (a1,a2,d,a3)
#define WS_WG 10240    // 24 frags (ot*2+ks)
#define WS_WV 22528    // 24 frags (ot*2+ks)
#define WS_FEATS 34816            // ushort offset of bf16 s_feats [M][192]
#define WS_NEED  (69632 + (size_t)NPTS*192*2)   // 7,749,632 bytes

typedef short bf16x8 __attribute__((ext_vector_type(8)));
typedef float f32x4  __attribute__((ext_vector_type(4)));

union BF8 { bf16x8 v; unsigned short us[8]; unsigned u[4]; };

__device__ __forceinline__ unsigned short f2bf(float f) {  // RNE, finite inputs
  unsigned u = __builtin_bit_cast(unsigned, f);
  u += 0x7fffu + ((u >> 16) & 1u);
  return (unsigned short)(u >> 16);
}
__device__ __forceinline__ float bfhi2f(unsigned hi) {     // hi = bf16 bits in [31:16]
  return __builtin_bit_cast(float, hi);
}
__device__ __forceinline__ unsigned pack2bf(float lo, float hi) {
  // v_cvt_pk_bf16_f32 on gfx950; low ushort = lo. (__hip_bfloat162 is not
  // trivially copyable -> bit_cast rejected; memcpy lowers to a reg move.)
  const __hip_bfloat162 h = __float22bfloat162_rn(make_float2(lo, hi));
  unsigned u;
  __builtin_memcpy(&u, &h, 4);
  return u;
}

__device__ __forceinline__ float fast_atan2pi(float y, float x) {
  // y >= 0; returns atan2(y,x)/pi; abs err ~1e-6
  const float ax = fabsf(x);
  const float mx = fmaxf(fmaxf(ax, y), 1e-30f);
  const float mn = fminf(ax, y);
  const float t  = mn * __builtin_amdgcn_rcpf(mx);
  const float s  = t * t;
  float p = -0.0117212f;
  p = fmaf(p, s,  0.05265332f);
  p = fmaf(p, s, -0.11643287f);
  p = fmaf(p, s,  0.19354346f);
  p = fmaf(p, s, -0.33262347f);
  p = fmaf(p, s,  0.99997726f);
  float r = p * t;
  if (y > ax)  r = 1.5707963268f - r;
  if (x < 0.f) r = 3.1415926536f - r;
  return r * 0.3183098862f;
}

__device__ __forceinline__ float angle3f(float ax, float ay, float az,
                                         float bx, float by, float bz) {
  const float y  = ax*bx + ay*by + az*bz;
  const float cx = ay*bz - az*by;
  const float cy = az*bx - ax*bz;
  const float cz = ax*by - ay*bx;
  const float xn = __builtin_amdgcn_sqrtf(cx*cx + cy*cy + cz*cz);
  return fast_atan2pi(xn, y);
}

// ---- prep: weights -> frag layout; feats -> bf16 [M][192]; one dispatch -----
// blocks 0..67: weight frags (64 threads used); blocks 68..1942: feats.
__global__ __launch_bounds__(256)
void prep_all(const float* __restrict__ sf,
              const float* __restrict__ W1, const float* __restrict__ W2,
              const float* __restrict__ W3, const float* __restrict__ Wg,
              const float* __restrict__ Wv, unsigned short* __restrict__ ws,
              int do_feats)
{
  const int b = blockIdx.x;
  if (b >= 68) {                       // feats: fp32 -> bf16, 8 floats/thread
    const int i = ((b - 68) * 256 + threadIdx.x) * 8;
    const float4 x = *(const float4*)&sf[i];
    const float4 y = *(const float4*)&sf[i + 4];
    uint4 w;
    w.x = f2bf(x.x) | ((unsigned)f2bf(x.y) << 16);
    w.y = f2bf(x.z) | ((unsigned)f2bf(x.w) << 16);
    w.z = f2bf(y.x) | ((unsigned)f2bf(y.y) << 16);
    w.w = f2bf(y.z) | ((unsigned)f2bf(y.w) << 16);
    *(uint4*)&ws[WS_FEATS + i] = w;
    return;
  }
  if (threadIdx.x >= 64) return;
  const int f  = b;                    // 68 weight frags
  const int L  = threadIdx.x;
  const int ln = L & 15, lq = L >> 4;
  unsigned short vals[8];
  if (f >= 16 && f < 20) {             // W1 [64][4]; K permuted (a1,a2,d,a3), pad 32
    const int ct = f - 16;
    const int perm[4] = {1, 2, 0, 3};  // ppf stored as (a1,a2,d,a3) in LDS
#pragma unroll
    for (int j = 0; j < 8; ++j) {
      const float v = (lq == 0 && j < 4) ? W1[(ln + 16*ct)*4 + perm[j]] : 0.f;
      vals[j] = f2bf(v);
    }
  } else {
    const float* M; int q;
    if (f < 8)       { M = W2; q = f; }
    else if (f < 16) { M = W3; q = f - 8; }
    else if (f < 44) { M = Wg; q = f - 20; }
    else             { M = Wv; q = f - 44; }
    const int ct = q >> 1, ks = q & 1;
    const float* src = M + (ln + 16*ct)*64 + lq*8 + 32*ks;
#pragma unroll
    for (int j = 0; j < 8; ++j) vals[j] = f2bf(src[j]);
  }
  uint4 w;
  w.x = vals[0] | ((unsigned)vals[1] << 16);
  w.y = vals[2] | ((unsigned)vals[3] << 16);
  w.z = vals[4] | ((unsigned)vals[5] << 16);
  w.w = vals[6] | ((unsigned)vals[7] << 16);
  *(uint4*)&ws[f*512 + L*8] = w;
  (void)do_feats;
}

// ---- main fused kernel ------------------------------------------------------
// NOTE: no gather buffers live across phases, and no gather helper functions —
// address-taken buffers (r4 ptr arg, r5 lambda) defeat SROA -> scratch spill.
// Layers 1-2 use SWAPPED MFMA operands: mfma(W-frag, h-frag) -> D[channel][nbr],
// so a lane's 4 regs are 4 consecutive channels of one h-row -> packed b64 store.
// LDS = s_h ONLY (17,408 B): after barrier #1 (h dead in all waves) the
// modb/aggb/gate/s_out regions are overlaid on s_h -> 8 blocks/CU (32 waves,
// 100% occupancy cap). Garbage rows in aliased frag reads only feed discarded
// D-rows (matmul row independence; residual bits are finite bf16).
template<bool BF>
__global__ __launch_bounds__(256, 8)
void ppf_fused(const float* __restrict__ q_pts,
               const float* __restrict__ s_pts,
               const float* __restrict__ s_feats,
               const int*   __restrict__ nbr,
               const float* __restrict__ normals,
               const float* __restrict__ b1, const float* __restrict__ b2,
               const float* __restrict__ b3, const float* __restrict__ bg,
               const unsigned short* __restrict__ wsu,
               float* __restrict__ out)
{
  // s_h rows: cols 0..63 = h tile (bf16); cols 64..67 = ppf (a1,a2,d,a3) bf16.
  __shared__ __align__(16) unsigned short s_h[PPB][KNB][68];   // 17408 B — ALL LDS
  unsigned short* s_base  = &s_h[0][0][0];
  unsigned short* s_modb  = s_base;              // 16 rows x 68 (rows 0..3 = points)
  unsigned short* s_gateb = s_base + 4*68;       // rows 4..15: 4x192 bf16 gate
  unsigned short* s_aggb  = s_base + 16*68;      // 16 rows x 68, rows=(g,t)
  float*          s_out   = (float*)(s_base + 2*16*68);  // 4 x 592 floats (13.8 KB end)

  const int tid  = threadIdx.x;
  const int g    = tid >> 6;
  const int lane = tid & 63;
  const int lq   = lane >> 4;
  const int ln   = lane & 15;
  const int pu   = __builtin_amdgcn_readfirstlane(blockIdx.x * PPB + g);

  // ---- Phase A: PPF features, split across wave halves ----------------------
  {
    const float qx = q_pts[pu*3+0], qy = q_pts[pu*3+1], qz = q_pts[pu*3+2];
    const int   i0 = nbr[pu*KNB];
    const float qnx = normals[i0*3+0], qny = normals[i0*3+1], qnz = normals[i0*3+2];
    const int k  = lane & 31;
    const int mi = nbr[pu*KNB + k];
    const float px = s_pts[mi*3+0], py = s_pts[mi*3+1], pz = s_pts[mi*3+2];
    const float nx = normals[mi*3+0], ny = normals[mi*3+1], nz = normals[mi*3+2];
    const float vx = px - qx, vy = py - qy, vz = pz - qz;
    unsigned* pp = (unsigned*)&s_h[g][k][64];
    if (lane < KNB) {
      const float a1v = angle3f(qnx,qny,qnz, vx,vy,vz);
      const float a2v = angle3f(nx,ny,nz,    vx,vy,vz);
      pp[0] = pack2bf(a1v, a2v);
    } else {
      const float dv  = __builtin_amdgcn_sqrtf(vx*vx + vy*vy + vz*vz);
      const float a3v = angle3f(qnx,qny,qnz, nx,ny,nz);
      pp[1] = pack2bf(dv, a3v);
    }
  }
  // ppf produced/consumed by the same wave; per-wave DS ops are in order.

  // ---- Layer 1 (swapped): relu(W1 @ ppf^T + b1) -> packed h rows ------------
  {
    BF8 pf[2];
    pf[0].u[0]=pf[0].u[1]=pf[0].u[2]=pf[0].u[3]=0;
    pf[1] = pf[0];
    if (lq == 0) {
#pragma unroll
      for (int rt = 0; rt < 2; ++rt) {
        const uint2 pv = *(const uint2*)&s_h[g][ln + 16*rt][64];
        pf[rt].u[0] = pv.x; pf[rt].u[1] = pv.y;   // (a1,a2,d,a3) bf16, k 4..31 = 0
      }
    }
#pragma unroll
    for (int ct = 0; ct < 4; ++ct) {
      const bf16x8 aw  = *(const bf16x8*)&wsu[WS_W1 + ct*512 + lane*8];
      const float4 bv4 = *(const float4*)&b1[ct*16 + lq*4];
#pragma unroll
      for (int rt = 0; rt < 2; ++rt) {
        f32x4 c = {bv4.x, bv4.y, bv4.z, bv4.w};
        c = __builtin_amdgcn_mfma_f32_16x16x32_bf16(aw, pf[rt].v, c, 0, 0, 0);
        uint2 pk;
        pk.x = pack2bf(fmaxf(c[0], 0.f), fmaxf(c[1], 0.f));
        pk.y = pack2bf(fmaxf(c[2], 0.f), fmaxf(c[3], 0.f));
        *(uint2*)&s_h[g][ln + 16*rt][ct*16 + lq*4] = pk;   // row=nbr, 4 channels
      }
    }
  }

  // ---- Layer 2 (swapped): relu(W2 @ h1^T + b2), in place --------------------
  // (in-place safe: the wave's 4 A-frag ds_reads precede all its ds_writes)
  {
    bf16x8 wf[8];
#pragma unroll
    for (int fIdx = 0; fIdx < 8; ++fIdx)
      wf[fIdx] = *(const bf16x8*)&wsu[WS_W2 + fIdx*512 + lane*8];
    bf16x8 hf[4];
#pragma unroll
    for (int rt = 0; rt < 2; ++rt)
#pragma unroll
      for (int ks = 0; ks < 2; ++ks)
        hf[rt*2+ks] = *(const bf16x8*)&s_h[g][ln + 16*rt][lq*8 + ks*32];
#pragma unroll
    for (int ct = 0; ct < 4; ++ct) {
      const float4 bv4 = *(const float4*)&b2[ct*16 + lq*4];
#pragma unroll
      for (int rt = 0; rt < 2; ++rt) {
        f32x4 c = {bv4.x, bv4.y, bv4.z, bv4.w};
        c = __builtin_amdgcn_mfma_f32_16x16x32_bf16(wf[ct*2+0], hf[rt*2+0], c, 0, 0, 0);
        c = __builtin_amdgcn_mfma_f32_16x16x32_bf16(wf[ct*2+1], hf[rt*2+1], c, 0, 0, 0);
        uint2 pk;
        pk.x = pack2bf(fmaxf(c[0], 0.f), fmaxf(c[1], 0.f));
        pk.y = pack2bf(fmaxf(c[2], 0.f), fmaxf(c[3], 0.f));
        *(uint2*)&s_h[g][ln + 16*rt][ct*16 + lq*4] = pk;
      }
    }
  }

  // ---- Layer 3 (unswapped) + K-mean kept in REGISTERS until barrier #1 ------
  float modv[4];   // col ln+16ct on lq==0 lanes (unrolled -> registers, no alloca)
  {
    bf16x8 wf[8];
#pragma unroll
    for (int fIdx = 0; fIdx < 8; ++fIdx)
      wf[fIdx] = *(const bf16x8*)&wsu[WS_W3 + fIdx*512 + lane*8];
    bf16x8 af[4];
#pragma unroll
    for (int rt = 0; rt < 2; ++rt)
#pragma unroll
      for (int ks = 0; ks < 2; ++ks)
        af[rt*2+ks] = *(const bf16x8*)&s_h[g][ln + 16*rt][lq*8 + ks*32];
#pragma unroll
    for (int ct = 0; ct < 4; ++ct) {
      const float bv = b3[ln + 16*ct];
      f32x4 c0 = {bv, bv, bv, bv};
      c0 = __builtin_amdgcn_mfma_f32_16x16x32_bf16(af[0], wf[ct*2+0], c0, 0, 0, 0);
      c0 = __builtin_amdgcn_mfma_f32_16x16x32_bf16(af[1], wf[ct*2+1], c0, 0, 0, 0);
      f32x4 c1 = {bv, bv, bv, bv};
      c1 = __builtin_amdgcn_mfma_f32_16x16x32_bf16(af[2], wf[ct*2+0], c1, 0, 0, 0);
      c1 = __builtin_amdgcn_mfma_f32_16x16x32_bf16(af[3], wf[ct*2+1], c1, 0, 0, 0);
      float s = (c0[0]+c0[1]+c0[2]+c0[3]) + (c1[0]+c1[1]+c1[2]+c1[3]);
      s += __shfl_xor(s, 16);
      s += __shfl_xor(s, 32);
      modv[ct] = s * (1.f/KNB);
    }
  }

  __syncthreads();   // barrier #1: all h/ppf reads done in ALL waves -> overlay live

  if (lq == 0) {
#pragma unroll
    for (int ct = 0; ct < 4; ++ct)
      s_modb[g*68 + ln + 16*ct] = f2bf(modv[ct]);
  }

  // ---- Neighbor-feature mean (inline loop; latency hidden by other waves) ---
  if constexpr (BF) {
    if (lane < 48) {
      float a0 = 0.f, a1 = 0.f, a2 = 0.f, a3 = 0.f;
      const unsigned short* fb = wsu + WS_FEATS;
      const int co = lane * 4;
#pragma unroll 8
      for (int k = 0; k < KNB; ++k) {
        const int mi = nbr[pu*KNB + k];              // wave-uniform -> s_load
        const uint2 v = *(const uint2*)&fb[(size_t)mi*192 + co];
        a0 += bfhi2f(v.x << 16); a1 += bfhi2f(v.x & 0xffff0000u);
        a2 += bfhi2f(v.y << 16); a3 += bfhi2f(v.y & 0xffff0000u);
      }
      // elements e = 4*lane + j, e = d*3 + t; s_aggb row n=(g,t), col=d
      const float av0 = a0 * (1.f/KNB), av1 = a1 * (1.f/KNB);
      const float av2 = a2 * (1.f/KNB), av3 = a3 * (1.f/KNB);
      const int e = 4*lane;
      s_aggb[(g*3 + ((e+0) % 3))*68 + (e+0)/3] = f2bf(av0);
      s_aggb[(g*3 + ((e+1) % 3))*68 + (e+1)/3] = f2bf(av1);
      s_aggb[(g*3 + ((e+2) % 3))*68 + (e+2)/3] = f2bf(av2);
      s_aggb[(g*3 + ((e+3) % 3))*68 + (e+3)/3] = f2bf(av3);
    }
  } else {
    float s0 = 0.f, s1 = 0.f, s2 = 0.f;
    const int lofs = lane * 3;
#pragma unroll 8
    for (int k = 0; k < KNB; ++k) {
      const int mi = nbr[pu*KNB + k];                // wave-uniform -> s_load
      const float* fr = s_feats + (size_t)mi*(DDIM*3) + lofs;
      s0 += fr[0]; s1 += fr[1]; s2 += fr[2];
    }
    s_aggb[(g*3+0)*68 + lane] = f2bf(s0 * (1.f/KNB));
    s_aggb[(g*3+1)*68 + lane] = f2bf(s1 * (1.f/KNB));
    s_aggb[(g*3+2)*68 + lane] = f2bf(s2 * (1.f/KNB));
  }

  __syncthreads();   // barrier #2: modb/aggb visible to all waves

  // ---- Gate via MFMA: rows = points (4 valid), cols = 192 outputs -----------
  // A-frag rows 4..15 are garbage (gate bits / dead h) — D rows 4..15 discarded.
  {
    const bf16x8 am0 = *(const bf16x8*)&s_modb[ln*68 + lq*8];
    const bf16x8 am1 = *(const bf16x8*)&s_modb[ln*68 + lq*8 + 32];
#pragma unroll
    for (int t = 0; t < 3; ++t) {
      const int ot = g*3 + t;
      const bf16x8 bg0 = *(const bf16x8*)&wsu[WS_WG + (ot*2+0)*512 + lane*8];
      const bf16x8 bg1 = *(const bf16x8*)&wsu[WS_WG + (ot*2+1)*512 + lane*8];
      const float  bv  = bg[ln + 16*ot];
      f32x4 c = {bv, bv, bv, bv};
      c = __builtin_amdgcn_mfma_f32_16x16x32_bf16(am0, bg0, c, 0, 0, 0);
      c = __builtin_amdgcn_mfma_f32_16x16x32_bf16(am1, bg1, c, 0, 0, 0);
      if (lq == 0) {
#pragma unroll
        for (int r = 0; r < 4; ++r)    // gate cols are per-wave partitioned
          s_gateb[r*192 + ln + 16*ot] = f2bf(1.f / (1.f + __expf(-c[r])));
      }
    }
  }

  // ---- Transform via MFMA: rows = outputs, cols = (point,t) -----------------
  {
    const bf16x8 ab0 = *(const bf16x8*)&s_aggb[ln*68 + lq*8];
    const bf16x8 ab1 = *(const bf16x8*)&s_aggb[ln*68 + lq*8 + 32];
    const int gi = ln / 3;            // valid for ln < 12
    const int tt = ln - gi*3;
#pragma unroll
    for (int t2 = 0; t2 < 3; ++t2) {
      const int ot = g*3 + t2;
      const bf16x8 av0 = *(const bf16x8*)&wsu[WS_WV + (ot*2+0)*512 + lane*8];
      const bf16x8 av1 = *(const bf16x8*)&wsu[WS_WV + (ot*2+1)*512 + lane*8];
      f32x4 c = {0.f, 0.f, 0.f, 0.f};
      c = __builtin_amdgcn_mfma_f32_16x16x32_bf16(av0, ab0, c, 0, 0, 0);
      c = __builtin_amdgcn_mfma_f32_16x16x32_bf16(av1, ab1, c, 0, 0, 0);
      if (ln < 12) {
#pragma unroll
        for (int r = 0; r < 4; ++r) {
          const int o = 16*ot + lq*4 + r;          // own col partition only
          const float gt = bfhi2f(((unsigned)s_gateb[gi*192 + o]) << 16);
          s_out[gi*592 + o*3 + tt] = c[r] * gt;    // s_out disjoint from frags
        }
      }
    }
  }
  __syncthreads();   // barrier #3: s_out complete

  // ---- Coalesced float4 output write ----------------------------------------
  {
    float4* outv = (float4*)out;
    const float4* sov = (const float4*)s_out;
#pragma unroll
    for (int i = 0; i < 3; ++i) {
      const int idx = tid + 256*i;
      if (idx < 576) {
        const int gg  = idx / 144;
        const int off = idx - gg*144;
        outv[(size_t)blockIdx.x * 576 + idx] = sov[gg*148 + off];
      }
    }
  }
}

extern "C" void kernel_launch(void* const* d_in, const int* in_sizes, int n_in,
                              void* d_out, int out_size, void* d_ws, size_t ws_size,
                              hipStream_t stream) {
  const float* q_pts   = (const float*)d_in[0];
  const float* s_pts   = (const float*)d_in[1];
  const float* s_feats = (const float*)d_in[2];
  const int*   nbr     = (const int*)  d_in[3];
  const float* normals = (const float*)d_in[4];
  const float* W1 = (const float*)d_in[5];
  const float* b1 = (const float*)d_in[6];
  const float* W2 = (const float*)d_in[7];
  const float* b2 = (const float*)d_in[8];
  const float* W3 = (const float*)d_in[9];
  const float* b3 = (const float*)d_in[10];
  const float* Wg = (const float*)d_in[11];
  const float* bg = (const float*)d_in[12];
  const float* Wv = (const float*)d_in[13];
  float* out = (float*)d_out;
  unsigned short* ws = (unsigned short*)d_ws;

  const int do_feats = (ws_size >= WS_NEED) ? 1 : 0;
  // feats: 20000*192 floats / 8 per thread / 256 per block = 1875 blocks
  const int prep_blocks = do_feats ? (68 + 1875) : 68;
  hipLaunchKernelGGL(prep_all, dim3(prep_blocks), dim3(256), 0, stream,
                     s_feats, W1, W2, W3, Wg, Wv, ws, do_feats);
  if (do_feats) {
    hipLaunchKernelGGL(ppf_fused<true>, dim3(NPTS / PPB), dim3(256), 0, stream,
                       q_pts, s_pts, s_feats, nbr, normals,
                       b1, b2, b3, bg, ws, out);
  } else {
    hipLaunchKernelGGL(ppf_fused<false>, dim3(NPTS / PPB), dim3(256), 0, stream,
                       q_pts, s_pts, s_feats, nbr, normals,
                       b1, b2, b3, bg, ws, out);
  }
}